// Round 1
// baseline (1535.377 us; speedup 1.0000x reference)
//
#include <hip/hip_runtime.h>
#include <math.h>

#define DIN 128
#define HD 64
#define NEG 0.2f

__device__ __forceinline__ float sigmoidf_(float x) { return 1.f / (1.f + __expf(-x)); }
__device__ __forceinline__ float tanhf_(float x)    { return 2.f / (1.f + __expf(-2.f*x)) - 1.f; }

// ---------------- CSR build ----------------
__global__ void k_zero_i(int* p, int n) {
  int i = blockIdx.x*256 + threadIdx.x;
  if (i < n) p[i] = 0;
}

__global__ void k_count(const int* __restrict__ dst, int E, int* __restrict__ deg) {
  int e = blockIdx.x*256 + threadIdx.x;
  if (e < E) atomicAdd(&deg[dst[e]], 1);
}

__global__ void k_scan1(const int* __restrict__ deg, int n, int* __restrict__ rowst, int* __restrict__ bsum) {
  __shared__ int s[256];
  int i = blockIdx.x*256 + threadIdx.x;
  int v = (i < n) ? deg[i] : 0;
  s[threadIdx.x] = v;
  __syncthreads();
  for (int off = 1; off < 256; off <<= 1) {
    int t = (threadIdx.x >= off) ? s[threadIdx.x - off] : 0;
    __syncthreads();
    s[threadIdx.x] += t;
    __syncthreads();
  }
  if (i < n) rowst[i] = s[threadIdx.x] - v;          // exclusive within block
  if (threadIdx.x == 255) bsum[blockIdx.x] = s[255]; // block total
}

__global__ void k_scan2(int* bsum, int nb) {
  __shared__ int s[256];
  int v = (threadIdx.x < nb) ? bsum[threadIdx.x] : 0;
  s[threadIdx.x] = v;
  __syncthreads();
  for (int off = 1; off < 256; off <<= 1) {
    int t = (threadIdx.x >= off) ? s[threadIdx.x - off] : 0;
    __syncthreads();
    s[threadIdx.x] += t;
    __syncthreads();
  }
  if (threadIdx.x < nb) bsum[threadIdx.x] = s[threadIdx.x] - v; // exclusive
}

__global__ void k_scan3(int* __restrict__ rowst, const int* __restrict__ bsum, int n, int E, int* __restrict__ deg) {
  int i = blockIdx.x*256 + threadIdx.x;
  if (i < n) { rowst[i] += bsum[blockIdx.x]; deg[i] = 0; } // deg reused as fill counter
  if (i == 0) rowst[n] = E;
}

__global__ void k_scatter(const int* __restrict__ src, const int* __restrict__ dst, int E,
                          const int* __restrict__ rowst, int* __restrict__ fill, int* __restrict__ csr) {
  int e = blockIdx.x*256 + threadIdx.x;
  if (e < E) {
    int d = dst[e];
    int pos = rowst[d] + atomicAdd(&fill[d], 1);
    csr[pos] = src[e];
  }
}

// ---------------- weight re-layout: WT[j][gate 0..5][k], gates 0..2=Wi r/z/n, 3..5=Wh ----------------
__global__ void k_wt(const float* __restrict__ Wi, const float* __restrict__ Wh, float* __restrict__ WT) {
  int i = blockIdx.x*256 + threadIdx.x;
  if (i < HD*6*HD) {
    int j = i / (6*HD), r = i % (6*HD), g = r / HD, k = r % HD;
    const float* W = (g < 3) ? Wi : Wh;
    WT[i] = W[k*(3*HD) + (g % 3)*HD + j];
  }
}

// ---------------- input projection + attention scalars (wave per node) ----------------
__global__ void k_proj(const float* __restrict__ x, const float* __restrict__ Win,
                       const float* __restrict__ bin, const float* __restrict__ aatt, int n,
                       float* __restrict__ h, float* __restrict__ ssrc, float* __restrict__ sdst) {
  __shared__ float Ws[DIN*HD];
  __shared__ float bs[HD];
  __shared__ float as2[2*HD];
  for (int i = threadIdx.x; i < DIN*HD; i += 256) Ws[i] = Win[i];
  if (threadIdx.x < HD) bs[threadIdx.x] = bin[threadIdx.x];
  if (threadIdx.x < 2*HD) as2[threadIdx.x] = aatt[threadIdx.x];
  __syncthreads();
  int wid = threadIdx.x >> 6, lane = threadIdx.x & 63;
  int node = blockIdx.x*4 + wid;
  if (node >= n) return;
  const float4* xr = (const float4*)(x + (size_t)node*DIN);
  float acc = bs[lane];
#pragma unroll
  for (int q = 0; q < DIN/4; ++q) {
    float4 xv = xr[q];
    acc += xv.x * Ws[(4*q+0)*HD + lane];
    acc += xv.y * Ws[(4*q+1)*HD + lane];
    acc += xv.z * Ws[(4*q+2)*HD + lane];
    acc += xv.w * Ws[(4*q+3)*HD + lane];
  }
  acc = fmaxf(acc, 0.f);
  h[(size_t)node*HD + lane] = acc;
  float p = acc * as2[lane], q2 = acc * as2[HD + lane];
#pragma unroll
  for (int off = 32; off; off >>= 1) { p += __shfl_xor(p, off); q2 += __shfl_xor(q2, off); }
  if (lane == 0) { ssrc[node] = p; sdst[node] = q2; }
}

// ---------------- attention aggregation: wave per node, online softmax over incoming edges ----------------
__global__ void k_agg(const float* __restrict__ h, const float* __restrict__ ssrc,
                      const float* __restrict__ sdst, const int* __restrict__ rowst,
                      const int* __restrict__ csr, int n, float* __restrict__ mout) {
  int wid = threadIdx.x >> 6, lane = threadIdx.x & 63;
  int node = blockIdx.x*4 + wid;
  if (node >= n) return;
  int s0 = rowst[node], s1 = rowst[node+1];
  float sdv = sdst[node];
  float runm = -INFINITY, runz = 0.f, acc = 0.f;
  int u_n = 0; float su_n = 0.f, hv_n = 0.f;
  if (s0 < s1) { u_n = csr[s0]; su_n = ssrc[u_n]; hv_n = h[(size_t)u_n*HD + lane]; }
  for (int i = s0; i < s1; ++i) {
    float su = su_n, hv = hv_n;
    if (i + 1 < s1) { int u2 = csr[i+1]; su_n = ssrc[u2]; hv_n = h[(size_t)u2*HD + lane]; }
    float sc = su + sdv;
    sc = (sc > 0.f) ? sc : NEG*sc;       // leaky_relu
    float nm = fmaxf(runm, sc);
    float scale = __expf(runm - nm);     // first iter: exp(-inf)=0
    float p = __expf(sc - nm);
    runz = runz*scale + p;
    acc  = acc*scale + p*hv;
    runm = nm;
  }
  mout[(size_t)node*HD + lane] = acc / (runz + 1e-16f);
}

// ---------------- GRU update (2 threads per node, k-split halves) + next-step attention scalars ----------------
__global__ void __launch_bounds__(256) k_gru(const float* __restrict__ mm, float* __restrict__ h,
                      const float* __restrict__ WT,
                      const float* __restrict__ bi, const float* __restrict__ bh,
                      const float* __restrict__ aatt, int n,
                      float* __restrict__ ssrc, float* __restrict__ sdst) {
  int t = blockIdx.x*256 + threadIdx.x;
  int node = t >> 1;
  if (node >= n) return;
  int half = t & 1;
  int ko = half << 5;                      // 0 or 32
  float mr[32], hr[32];
  const float4* m4 = (const float4*)(mm + (size_t)node*HD + ko);
  const float4* h4 = (const float4*)(h  + (size_t)node*HD + ko);
#pragma unroll
  for (int q = 0; q < 8; ++q) {
    float4 a = m4[q];
    mr[4*q] = a.x; mr[4*q+1] = a.y; mr[4*q+2] = a.z; mr[4*q+3] = a.w;
  }
#pragma unroll
  for (int q = 0; q < 8; ++q) {
    float4 b = h4[q];
    hr[4*q] = b.x; hr[4*q+1] = b.y; hr[4*q+2] = b.z; hr[4*q+3] = b.w;
  }
  float ps = 0.f, pd = 0.f;
#pragma unroll 2
  for (int j = 0; j < HD; ++j) {
    const float* wb = WT + j*(6*HD) + ko;
    const float4* w0 = (const float4*)(wb + 0*HD);
    const float4* w1 = (const float4*)(wb + 1*HD);
    const float4* w2 = (const float4*)(wb + 2*HD);
    const float4* w3 = (const float4*)(wb + 3*HD);
    const float4* w4 = (const float4*)(wb + 4*HD);
    const float4* w5 = (const float4*)(wb + 5*HD);
    float ar = 0.f, az = 0.f, an = 0.f, br = 0.f, bz = 0.f, bn = 0.f;
#pragma unroll
    for (int q = 0; q < 8; ++q) {
      float4 wa = w0[q], wbv = w1[q], wc = w2[q], wd = w3[q], we = w4[q], wf = w5[q];
      float m0 = mr[4*q], m1 = mr[4*q+1], m2 = mr[4*q+2], m3 = mr[4*q+3];
      float h0 = hr[4*q], h1 = hr[4*q+1], h2 = hr[4*q+2], h3 = hr[4*q+3];
      ar += m0*wa.x  + m1*wa.y  + m2*wa.z  + m3*wa.w;
      az += m0*wbv.x + m1*wbv.y + m2*wbv.z + m3*wbv.w;
      an += m0*wc.x  + m1*wc.y  + m2*wc.z  + m3*wc.w;
      br += h0*wd.x  + h1*wd.y  + h2*wd.z  + h3*wd.w;
      bz += h0*we.x  + h1*we.y  + h2*we.z  + h3*we.w;
      bn += h0*wf.x  + h1*wf.y  + h2*wf.z  + h3*wf.w;
    }
    ar += __shfl_xor(ar, 1); az += __shfl_xor(az, 1); an += __shfl_xor(an, 1);
    br += __shfl_xor(br, 1); bz += __shfl_xor(bz, 1); bn += __shfl_xor(bn, 1);
    float rg = sigmoidf_(ar + br + bi[j] + bh[j]);
    float zg = sigmoidf_(az + bz + bi[HD + j] + bh[HD + j]);
    float ng = tanhf_(an + bi[2*HD + j] + rg*(bn + bh[2*HD + j]));
    if ((j >> 5) == half) {                // owner lane updates h[j]
      size_t idx = (size_t)node*HD + j;
      float hold = h[idx];                 // not yet overwritten at iter j
      float hnew = (1.f - zg)*ng + zg*hold;
      h[idx] = hnew;
      ps += hnew * aatt[j];
      pd += hnew * aatt[HD + j];
    }
  }
  ps += __shfl_xor(ps, 1); pd += __shfl_xor(pd, 1);
  if (half == 0) { ssrc[node] = ps; sdst[node] = pd; }
}

// ---------------- pooling (block per graph) ----------------
__device__ __forceinline__ int lower_bound_i(const int* a, int n, int key) {
  int lo = 0, hi = n;
  while (lo < hi) { int mid = (lo + hi) >> 1; if (a[mid] < key) lo = mid + 1; else hi = mid; }
  return lo;
}

__global__ void k_pool(const float* __restrict__ h, const int* __restrict__ batch, int n,
                       float* __restrict__ gpool) {
  int g = blockIdx.x;
  int lo = lower_bound_i(batch, n, g);
  int hi = lower_bound_i(batch, n, g + 1);
  int wid = threadIdx.x >> 6, lane = threadIdx.x & 63;
  float sum = 0.f, mx = -INFINITY;
  for (int i = lo + wid; i < hi; i += 4) {
    float v = h[(size_t)i*HD + lane];
    sum += v; mx = fmaxf(mx, v);
  }
  __shared__ float ssum[4][HD], smax[4][HD];
  ssum[wid][lane] = sum; smax[wid][lane] = mx;
  __syncthreads();
  if (wid == 0) {
    sum = ssum[0][lane] + ssum[1][lane] + ssum[2][lane] + ssum[3][lane];
    mx = fmaxf(fmaxf(smax[0][lane], smax[1][lane]), fmaxf(smax[2][lane], smax[3][lane]));
    int cnt = hi - lo;
    float mean = sum / fmaxf((float)cnt, 1.f);
    if (cnt <= 0) mx = 0.f;                 // isfinite(maxp) handling
    gpool[(size_t)g*2*HD + lane] = mean;
    gpool[(size_t)g*2*HD + HD + lane] = mx;
  }
}

// ---------------- MLP head (block per graph, one wave) ----------------
__global__ void k_head(const float* __restrict__ gpool, const float* __restrict__ W1,
                       const float* __restrict__ b1, const float* __restrict__ W2,
                       const float* __restrict__ b2, float* __restrict__ out) {
  int g = blockIdx.x, j = threadIdx.x;
  const float* gr = gpool + (size_t)g*2*HD;
  float acc = b1[j];
#pragma unroll
  for (int k = 0; k < 2*HD; ++k) acc += gr[k] * W1[k*HD + j];
  acc = fmaxf(acc, 0.f);
  float v = acc * W2[j];
#pragma unroll
  for (int off = 32; off; off >>= 1) v += __shfl_xor(v, off);
  if (j == 0) out[g] = v + b2[0];
}

extern "C" void kernel_launch(void* const* d_in, const int* in_sizes, int n_in,
                              void* d_out, int out_size, void* d_ws, size_t ws_size,
                              hipStream_t stream) {
  const float* x     = (const float*)d_in[0];
  const int*   ei    = (const int*)d_in[1];
  const int*   batch = (const int*)d_in[2];
  const float* Win   = (const float*)d_in[3];
  const float* bin   = (const float*)d_in[4];
  const float* aatt  = (const float*)d_in[5];
  const float* Wi    = (const float*)d_in[6];
  const float* Wh    = (const float*)d_in[7];
  const float* bi    = (const float*)d_in[8];
  const float* bh    = (const float*)d_in[9];
  const float* W1    = (const float*)d_in[10];
  const float* b1    = (const float*)d_in[11];
  const float* W2    = (const float*)d_in[12];
  const float* b2    = (const float*)d_in[13];
  float* out = (float*)d_out;

  int N = in_sizes[0] / DIN;
  int E = in_sizes[1] / 2;
  int G = out_size;              // DOUT == 1

  const int* srcp = ei;
  const int* dstp = ei + E;

  char* base = (char*)d_ws;
  size_t off = 0;
  auto alloc = [&](size_t bytes) -> char* {
    char* p = base + off;
    off += (bytes + 255) & ~(size_t)255;
    return p;
  };
  float* h     = (float*)alloc((size_t)N*HD*4);
  float* mbuf  = (float*)alloc((size_t)N*HD*4);
  float* ssrc  = (float*)alloc((size_t)N*4);
  float* sdst  = (float*)alloc((size_t)N*4);
  int*   deg   = (int*)  alloc((size_t)N*4);
  int*   rowst = (int*)  alloc((size_t)(N+1)*4);
  int*   csr   = (int*)  alloc((size_t)E*4);
  float* WT    = (float*)alloc((size_t)HD*6*HD*4);
  float* gpool = (float*)alloc((size_t)G*2*HD*4);
  int*   bsum  = (int*)  alloc(1024);
  (void)ws_size; (void)n_in;

  int nbN = (N + 255)/256, nbE = (E + 255)/256;

  k_zero_i<<<nbN, 256, 0, stream>>>(deg, N);
  k_count<<<nbE, 256, 0, stream>>>(dstp, E, deg);
  k_scan1<<<nbN, 256, 0, stream>>>(deg, N, rowst, bsum);
  k_scan2<<<1, 256, 0, stream>>>(bsum, nbN);
  k_scan3<<<nbN, 256, 0, stream>>>(rowst, bsum, N, E, deg);
  k_scatter<<<nbE, 256, 0, stream>>>(srcp, dstp, E, rowst, deg, csr);
  k_wt<<<(HD*6*HD + 255)/256, 256, 0, stream>>>(Wi, Wh, WT);
  k_proj<<<(N + 3)/4, 256, 0, stream>>>(x, Win, bin, aatt, N, h, ssrc, sdst);
  for (int t = 0; t < 3; ++t) {
    k_agg<<<(N + 3)/4, 256, 0, stream>>>(h, ssrc, sdst, rowst, csr, N, mbuf);
    k_gru<<<(2*N + 255)/256, 256, 0, stream>>>(mbuf, h, WT, bi, bh, aatt, N, ssrc, sdst);
  }
  k_pool<<<G, 256, 0, stream>>>(h, batch, N, gpool);
  k_head<<<G, 64, 0, stream>>>(gpool, W1, b1, W2, b2, out);
}

// Round 2
// 645.474 us; speedup vs baseline: 2.3787x; 2.3787x over previous
//
#include <hip/hip_runtime.h>
#include <math.h>

#define DIN 128
#define HD 64
#define NEG 0.2f

__device__ __forceinline__ float sigmoidf_(float x) { return 1.f / (1.f + __expf(-x)); }
__device__ __forceinline__ float tanhf_(float x)    { return 2.f / (1.f + __expf(-2.f*x)) - 1.f; }

// ---------------- CSR build ----------------
__global__ void k_zero_i(int* p, int n) {
  int i = blockIdx.x*256 + threadIdx.x;
  if (i < n) p[i] = 0;
}

__global__ void k_count(const int* __restrict__ dst, int E, int* __restrict__ deg) {
  int e = blockIdx.x*256 + threadIdx.x;
  if (e < E) atomicAdd(&deg[dst[e]], 1);
}

__global__ void k_scan1(const int* __restrict__ deg, int n, int* __restrict__ rowst, int* __restrict__ bsum) {
  __shared__ int s[256];
  int i = blockIdx.x*256 + threadIdx.x;
  int v = (i < n) ? deg[i] : 0;
  s[threadIdx.x] = v;
  __syncthreads();
  for (int off = 1; off < 256; off <<= 1) {
    int t = (threadIdx.x >= off) ? s[threadIdx.x - off] : 0;
    __syncthreads();
    s[threadIdx.x] += t;
    __syncthreads();
  }
  if (i < n) rowst[i] = s[threadIdx.x] - v;          // exclusive within block
  if (threadIdx.x == 255) bsum[blockIdx.x] = s[255]; // block total
}

__global__ void k_scan2(int* bsum, int nb) {
  __shared__ int s[256];
  int v = (threadIdx.x < nb) ? bsum[threadIdx.x] : 0;
  s[threadIdx.x] = v;
  __syncthreads();
  for (int off = 1; off < 256; off <<= 1) {
    int t = (threadIdx.x >= off) ? s[threadIdx.x - off] : 0;
    __syncthreads();
    s[threadIdx.x] += t;
    __syncthreads();
  }
  if (threadIdx.x < nb) bsum[threadIdx.x] = s[threadIdx.x] - v; // exclusive
}

__global__ void k_scan3(int* __restrict__ rowst, const int* __restrict__ bsum, int n, int E, int* __restrict__ deg) {
  int i = blockIdx.x*256 + threadIdx.x;
  if (i < n) { rowst[i] += bsum[blockIdx.x]; deg[i] = 0; } // deg reused as fill counter
  if (i == 0) rowst[n] = E;
}

__global__ void k_scatter(const int* __restrict__ src, const int* __restrict__ dst, int E,
                          const int* __restrict__ rowst, int* __restrict__ fill, int* __restrict__ csr) {
  int e = blockIdx.x*256 + threadIdx.x;
  if (e < E) {
    int d = dst[e];
    int pos = rowst[d] + atomicAdd(&fill[d], 1);
    csr[pos] = src[e];
  }
}

// ---------------- GRU weight re-layout ----------------
// B[k][c], k in [0,128): k<64 -> m-row (Wi), k>=64 -> h-row (Wh).
// c = j*4 + gate; gate 0: r-sum (Wi_r/Wh_r), 1: z-sum, 2: gi_n (Wi only), 3: gh_n (Wh only)
// bc[c]: combined bias for that column.
__global__ void k_wt2(const float* __restrict__ Wi, const float* __restrict__ Wh,
                      const float* __restrict__ bi, const float* __restrict__ bh,
                      float* __restrict__ B, float* __restrict__ bc) {
  int i = blockIdx.x*256 + threadIdx.x;
  if (i < 128*256) {
    int k = i >> 8, c = i & 255;
    int j = c >> 2, g = c & 3;
    float v;
    if (g == 0)      v = (k < 64) ? Wi[k*(3*HD) + j]        : Wh[(k-64)*(3*HD) + j];
    else if (g == 1) v = (k < 64) ? Wi[k*(3*HD) + HD + j]   : Wh[(k-64)*(3*HD) + HD + j];
    else if (g == 2) v = (k < 64) ? Wi[k*(3*HD) + 2*HD + j] : 0.f;
    else             v = (k < 64) ? 0.f                     : Wh[(k-64)*(3*HD) + 2*HD + j];
    B[i] = v;
  }
  if (i < 256) {
    int j = i >> 2, g = i & 3;
    float v;
    if (g == 0)      v = bi[j] + bh[j];
    else if (g == 1) v = bi[HD + j] + bh[HD + j];
    else if (g == 2) v = bi[2*HD + j];
    else             v = bh[2*HD + j];
    bc[i] = v;
  }
}

// ---------------- input projection + attention scalars (wave per node) ----------------
__global__ void k_proj(const float* __restrict__ x, const float* __restrict__ Win,
                       const float* __restrict__ bin, const float* __restrict__ aatt, int n,
                       float* __restrict__ h, float* __restrict__ ssrc, float* __restrict__ sdst) {
  __shared__ float Ws[DIN*HD];
  __shared__ float bs[HD];
  __shared__ float as2[2*HD];
  for (int i = threadIdx.x; i < DIN*HD; i += 256) Ws[i] = Win[i];
  if (threadIdx.x < HD) bs[threadIdx.x] = bin[threadIdx.x];
  if (threadIdx.x < 2*HD) as2[threadIdx.x] = aatt[threadIdx.x];
  __syncthreads();
  int wid = threadIdx.x >> 6, lane = threadIdx.x & 63;
  int node = blockIdx.x*4 + wid;
  if (node >= n) return;
  const float4* xr = (const float4*)(x + (size_t)node*DIN);
  float acc = bs[lane];
#pragma unroll
  for (int q = 0; q < DIN/4; ++q) {
    float4 xv = xr[q];
    acc += xv.x * Ws[(4*q+0)*HD + lane];
    acc += xv.y * Ws[(4*q+1)*HD + lane];
    acc += xv.z * Ws[(4*q+2)*HD + lane];
    acc += xv.w * Ws[(4*q+3)*HD + lane];
  }
  acc = fmaxf(acc, 0.f);
  h[(size_t)node*HD + lane] = acc;
  float p = acc * as2[lane], q2 = acc * as2[HD + lane];
#pragma unroll
  for (int off = 32; off; off >>= 1) { p += __shfl_xor(p, off); q2 += __shfl_xor(q2, off); }
  if (lane == 0) { ssrc[node] = p; sdst[node] = q2; }
}

// ---------------- attention aggregation: wave per node, online softmax over incoming edges ----------------
__global__ void k_agg(const float* __restrict__ h, const float* __restrict__ ssrc,
                      const float* __restrict__ sdst, const int* __restrict__ rowst,
                      const int* __restrict__ csr, int n, float* __restrict__ mout) {
  int wid = threadIdx.x >> 6, lane = threadIdx.x & 63;
  int node = blockIdx.x*4 + wid;
  if (node >= n) return;
  int s0 = rowst[node], s1 = rowst[node+1];
  float sdv = sdst[node];
  float runm = -INFINITY, runz = 0.f, acc = 0.f;
  int u_n = 0; float su_n = 0.f, hv_n = 0.f;
  if (s0 < s1) { u_n = csr[s0]; su_n = ssrc[u_n]; hv_n = h[(size_t)u_n*HD + lane]; }
  for (int i = s0; i < s1; ++i) {
    float su = su_n, hv = hv_n;
    if (i + 1 < s1) { int u2 = csr[i+1]; su_n = ssrc[u2]; hv_n = h[(size_t)u2*HD + lane]; }
    float sc = su + sdv;
    sc = (sc > 0.f) ? sc : NEG*sc;       // leaky_relu
    float nm = fmaxf(runm, sc);
    float scale = __expf(runm - nm);     // first iter: exp(-inf)=0
    float p = __expf(sc - nm);
    runz = runz*scale + p;
    acc  = acc*scale + p*hv;
    runm = nm;
  }
  mout[(size_t)node*HD + lane] = acc / (runz + 1e-16f);
}

// ---------------- GRU as register-blocked fp32 GEMM ----------------
// C[64 nodes][256 cols] per block; 256 threads; each thread 8 nodes x 8 cols (= 2 j values x 4 gates).
// A = concat(m, h) staged transposed in LDS: A[k][m_local], k in [0,128).
// B streamed from global (L1/L2-resident, 128KB shared by all blocks).
__global__ void __launch_bounds__(256) k_gru2(const float* __restrict__ mm, float* __restrict__ h,
                      const float* __restrict__ B, const float* __restrict__ bc,
                      const float* __restrict__ aatt, int n,
                      float* __restrict__ ssrc, float* __restrict__ sdst) {
  __shared__ float A[128][64];   // 32KB
  int m_base = blockIdx.x * 64;
  int tx = threadIdx.x;

  // ---- stage A (transposed): 4 threads per node, 8 float4 each ----
  {
    int m = tx & 63;
    int kq4 = tx >> 6;           // 0..3
    int node = m_base + m;
    bool valid = node < n;
    const float4* m4 = (const float4*)(mm + (size_t)node*HD);
    const float4* h4 = (const float4*)(h  + (size_t)node*HD);
#pragma unroll
    for (int it = 0; it < 8; ++it) {
      int kq = kq4*8 + it;       // 0..31 (float4 index over 128 k)
      int k0 = kq*4;
      float4 v = make_float4(0.f,0.f,0.f,0.f);
      if (valid) v = (kq < 16) ? m4[kq] : h4[kq - 16];
      A[k0+0][m] = v.x; A[k0+1][m] = v.y; A[k0+2][m] = v.z; A[k0+3][m] = v.w;
    }
  }
  __syncthreads();

  int n_idx = tx & 31;
  int m_idx = tx >> 5;           // 0..7
  int c0 = n_idx * 8;            // 8 cols = 2 j's x 4 gates
  int m0 = m_idx * 8;            // 8 nodes

  float acc[8][8];
#pragma unroll
  for (int a = 0; a < 8; ++a)
#pragma unroll
    for (int b = 0; b < 8; ++b) acc[a][b] = 0.f;

#pragma unroll 4
  for (int k = 0; k < 128; ++k) {
    float4 b0 = *(const float4*)(B + k*256 + c0);
    float4 b1 = *(const float4*)(B + k*256 + c0 + 4);
    float4 a0 = *(const float4*)(&A[k][m0]);
    float4 a1 = *(const float4*)(&A[k][m0+4]);
    float av[8] = {a0.x,a0.y,a0.z,a0.w,a1.x,a1.y,a1.z,a1.w};
    float bv[8] = {b0.x,b0.y,b0.z,b0.w,b1.x,b1.y,b1.z,b1.w};
#pragma unroll
    for (int a = 0; a < 8; ++a)
#pragma unroll
      for (int b = 0; b < 8; ++b) acc[a][b] += av[a]*bv[b];
  }

  // combined biases for this thread's 8 cols
  float4 bcv0 = *(const float4*)(bc + c0);
  float4 bcv1 = *(const float4*)(bc + c0 + 4);
  float bcr[8] = {bcv0.x,bcv0.y,bcv0.z,bcv0.w,bcv1.x,bcv1.y,bcv1.z,bcv1.w};

  int j0 = c0 >> 2;              // first j
  float a_s0 = aatt[j0],   a_s1 = aatt[j0+1];
  float a_d0 = aatt[HD+j0], a_d1 = aatt[HD+j0+1];

#pragma unroll
  for (int a = 0; a < 8; ++a) {
    int ml = m0 + a;
    int node = m_base + ml;
    float ps = 0.f, pd = 0.f;
#pragma unroll
    for (int jj = 0; jj < 2; ++jj) {
      int j = j0 + jj;
      float r   = acc[a][jj*4+0] + bcr[jj*4+0];
      float z   = acc[a][jj*4+1] + bcr[jj*4+1];
      float gin = acc[a][jj*4+2] + bcr[jj*4+2];
      float ghn = acc[a][jj*4+3] + bcr[jj*4+3];
      float rg = sigmoidf_(r);
      float zg = sigmoidf_(z);
      float ng = tanhf_(gin + rg*ghn);
      float hold = A[64+j][ml];
      float hnew = (1.f - zg)*ng + zg*hold;
      if (node < n) h[(size_t)node*HD + j] = hnew;
      ps += hnew * (jj ? a_s1 : a_s0);
      pd += hnew * (jj ? a_d1 : a_d0);
    }
    // reduce over the 32 n_idx lanes (xor<32 stays within the half-wave)
#pragma unroll
    for (int off = 16; off; off >>= 1) { ps += __shfl_xor(ps, off); pd += __shfl_xor(pd, off); }
    if (n_idx == 0 && node < n) { ssrc[node] = ps; sdst[node] = pd; }
  }
}

// ---------------- pooling (block per graph) ----------------
__device__ __forceinline__ int lower_bound_i(const int* a, int n, int key) {
  int lo = 0, hi = n;
  while (lo < hi) { int mid = (lo + hi) >> 1; if (a[mid] < key) lo = mid + 1; else hi = mid; }
  return lo;
}

__global__ void k_pool(const float* __restrict__ h, const int* __restrict__ batch, int n,
                       float* __restrict__ gpool) {
  int g = blockIdx.x;
  int lo = lower_bound_i(batch, n, g);
  int hi = lower_bound_i(batch, n, g + 1);
  int wid = threadIdx.x >> 6, lane = threadIdx.x & 63;
  float sum = 0.f, mx = -INFINITY;
  for (int i = lo + wid; i < hi; i += 4) {
    float v = h[(size_t)i*HD + lane];
    sum += v; mx = fmaxf(mx, v);
  }
  __shared__ float ssum[4][HD], smax[4][HD];
  ssum[wid][lane] = sum; smax[wid][lane] = mx;
  __syncthreads();
  if (wid == 0) {
    sum = ssum[0][lane] + ssum[1][lane] + ssum[2][lane] + ssum[3][lane];
    mx = fmaxf(fmaxf(smax[0][lane], smax[1][lane]), fmaxf(smax[2][lane], smax[3][lane]));
    int cnt = hi - lo;
    float mean = sum / fmaxf((float)cnt, 1.f);
    if (cnt <= 0) mx = 0.f;                 // isfinite(maxp) handling
    gpool[(size_t)g*2*HD + lane] = mean;
    gpool[(size_t)g*2*HD + HD + lane] = mx;
  }
}

// ---------------- MLP head (block per graph, one wave) ----------------
__global__ void k_head(const float* __restrict__ gpool, const float* __restrict__ W1,
                       const float* __restrict__ b1, const float* __restrict__ W2,
                       const float* __restrict__ b2, float* __restrict__ out) {
  int g = blockIdx.x, j = threadIdx.x;
  const float* gr = gpool + (size_t)g*2*HD;
  float acc = b1[j];
#pragma unroll
  for (int k = 0; k < 2*HD; ++k) acc += gr[k] * W1[k*HD + j];
  acc = fmaxf(acc, 0.f);
  float v = acc * W2[j];
#pragma unroll
  for (int off = 32; off; off >>= 1) v += __shfl_xor(v, off);
  if (j == 0) out[g] = v + b2[0];
}

extern "C" void kernel_launch(void* const* d_in, const int* in_sizes, int n_in,
                              void* d_out, int out_size, void* d_ws, size_t ws_size,
                              hipStream_t stream) {
  const float* x     = (const float*)d_in[0];
  const int*   ei    = (const int*)d_in[1];
  const int*   batch = (const int*)d_in[2];
  const float* Win   = (const float*)d_in[3];
  const float* bin   = (const float*)d_in[4];
  const float* aatt  = (const float*)d_in[5];
  const float* Wi    = (const float*)d_in[6];
  const float* Wh    = (const float*)d_in[7];
  const float* bi    = (const float*)d_in[8];
  const float* bh    = (const float*)d_in[9];
  const float* W1    = (const float*)d_in[10];
  const float* b1    = (const float*)d_in[11];
  const float* W2    = (const float*)d_in[12];
  const float* b2    = (const float*)d_in[13];
  float* out = (float*)d_out;

  int N = in_sizes[0] / DIN;
  int E = in_sizes[1] / 2;
  int G = out_size;              // DOUT == 1

  const int* srcp = ei;
  const int* dstp = ei + E;

  char* base = (char*)d_ws;
  size_t off = 0;
  auto alloc = [&](size_t bytes) -> char* {
    char* p = base + off;
    off += (bytes + 255) & ~(size_t)255;
    return p;
  };
  float* h     = (float*)alloc((size_t)N*HD*4);
  float* mbuf  = (float*)alloc((size_t)N*HD*4);
  float* ssrc  = (float*)alloc((size_t)N*4);
  float* sdst  = (float*)alloc((size_t)N*4);
  int*   deg   = (int*)  alloc((size_t)N*4);
  int*   rowst = (int*)  alloc((size_t)(N+1)*4);
  int*   csr   = (int*)  alloc((size_t)E*4);
  float* B     = (float*)alloc((size_t)128*256*4);
  float* bc    = (float*)alloc((size_t)256*4);
  float* gpool = (float*)alloc((size_t)G*2*HD*4);
  int*   bsum  = (int*)  alloc(1024);
  (void)ws_size; (void)n_in;

  int nbN = (N + 255)/256, nbE = (E + 255)/256;

  k_zero_i<<<nbN, 256, 0, stream>>>(deg, N);
  k_count<<<nbE, 256, 0, stream>>>(dstp, E, deg);
  k_scan1<<<nbN, 256, 0, stream>>>(deg, N, rowst, bsum);
  k_scan2<<<1, 256, 0, stream>>>(bsum, nbN);
  k_scan3<<<nbN, 256, 0, stream>>>(rowst, bsum, N, E, deg);
  k_scatter<<<nbE, 256, 0, stream>>>(srcp, dstp, E, rowst, deg, csr);
  k_wt2<<<(128*256 + 255)/256, 256, 0, stream>>>(Wi, Wh, bi, bh, B, bc);
  k_proj<<<(N + 3)/4, 256, 0, stream>>>(x, Win, bin, aatt, N, h, ssrc, sdst);
  for (int t = 0; t < 3; ++t) {
    k_agg<<<(N + 3)/4, 256, 0, stream>>>(h, ssrc, sdst, rowst, csr, N, mbuf);
    k_gru2<<<(N + 63)/64, 256, 0, stream>>>(mbuf, h, B, bc, aatt, N, ssrc, sdst);
  }
  k_pool<<<G, 256, 0, stream>>>(h, batch, N, gpool);
  k_head<<<G, 64, 0, stream>>>(gpool, W1, b1, W2, b2, out);
}

// Round 3
// 523.663 us; speedup vs baseline: 2.9320x; 1.2326x over previous
//
#include <hip/hip_runtime.h>
#include <math.h>

#define DIN 128
#define HD 64
#define NEG 0.2f

__device__ __forceinline__ float sigmoidf_(float x) { return 1.f / (1.f + __expf(-x)); }
__device__ __forceinline__ float tanhf_(float x)    { return 2.f / (1.f + __expf(-2.f*x)) - 1.f; }

// ---------------- CSR build ----------------
__global__ void k_count(const int* __restrict__ dst, int E, int* __restrict__ deg) {
  int e = blockIdx.x*256 + threadIdx.x;
  if (e < E) atomicAdd(&deg[dst[e]], 1);
}

__global__ void k_scan1(const int* __restrict__ deg, int n, int* __restrict__ rowst, int* __restrict__ bsum) {
  __shared__ int s[256];
  int i = blockIdx.x*256 + threadIdx.x;
  int v = (i < n) ? deg[i] : 0;
  s[threadIdx.x] = v;
  __syncthreads();
  for (int off = 1; off < 256; off <<= 1) {
    int t = (threadIdx.x >= off) ? s[threadIdx.x - off] : 0;
    __syncthreads();
    s[threadIdx.x] += t;
    __syncthreads();
  }
  if (i < n) rowst[i] = s[threadIdx.x] - v;          // exclusive within block
  if (threadIdx.x == 255) bsum[blockIdx.x] = s[255]; // block total
}

__global__ void k_scan2(int* bsum, int nb) {
  __shared__ int s[256];
  int v = (threadIdx.x < nb) ? bsum[threadIdx.x] : 0;
  s[threadIdx.x] = v;
  __syncthreads();
  for (int off = 1; off < 256; off <<= 1) {
    int t = (threadIdx.x >= off) ? s[threadIdx.x - off] : 0;
    __syncthreads();
    s[threadIdx.x] += t;
    __syncthreads();
  }
  if (threadIdx.x < nb) bsum[threadIdx.x] = s[threadIdx.x] - v; // exclusive
}

__global__ void k_scan3(int* __restrict__ rowst, const int* __restrict__ bsum, int n, int E, int* __restrict__ deg) {
  int i = blockIdx.x*256 + threadIdx.x;
  if (i < n) { rowst[i] += bsum[blockIdx.x]; deg[i] = 0; } // deg reused as fill counter
  if (i == 0) rowst[n] = E;
}

__global__ void k_scatter(const int* __restrict__ src, const int* __restrict__ dst, int E,
                          const int* __restrict__ rowst, int* __restrict__ fill, int* __restrict__ csr) {
  int e = blockIdx.x*256 + threadIdx.x;
  if (e < E) {
    int d = dst[e];
    int pos = rowst[d] + atomicAdd(&fill[d], 1);
    csr[pos] = src[e];
  }
}

// ---------------- GRU weight re-layout ----------------
// B[k][c], k in [0,128): k<64 -> m-row (Wi), k>=64 -> h-row (Wh).
// c = j*4 + gate; gate 0: r-sum, 1: z-sum, 2: gi_n (Wi only), 3: gh_n (Wh only)
__global__ void k_wt2(const float* __restrict__ Wi, const float* __restrict__ Wh,
                      const float* __restrict__ bi, const float* __restrict__ bh,
                      float* __restrict__ B, float* __restrict__ bc) {
  int i = blockIdx.x*256 + threadIdx.x;
  if (i < 128*256) {
    int k = i >> 8, c = i & 255;
    int j = c >> 2, g = c & 3;
    float v;
    if (g == 0)      v = (k < 64) ? Wi[k*(3*HD) + j]        : Wh[(k-64)*(3*HD) + j];
    else if (g == 1) v = (k < 64) ? Wi[k*(3*HD) + HD + j]   : Wh[(k-64)*(3*HD) + HD + j];
    else if (g == 2) v = (k < 64) ? Wi[k*(3*HD) + 2*HD + j] : 0.f;
    else             v = (k < 64) ? 0.f                     : Wh[(k-64)*(3*HD) + 2*HD + j];
    B[i] = v;
  }
  if (i < 256) {
    int j = i >> 2, g = i & 3;
    float v;
    if (g == 0)      v = bi[j] + bh[j];
    else if (g == 1) v = bi[HD + j] + bh[HD + j];
    else if (g == 2) v = bi[2*HD + j];
    else             v = bh[2*HD + j];
    bc[i] = v;
  }
}

// ---------------- input projection as register-blocked GEMM ----------------
// C[64 nodes][64 cols] per block; 256 threads; each thread 8 nodes x 2 cols.
// A = x staged transposed in LDS: A[k][m_local], k in [0,128). W_in streamed (L1-hot, 32KB).
__global__ void __launch_bounds__(256) k_proj2(const float* __restrict__ x, const float* __restrict__ Win,
                       const float* __restrict__ bin, const float* __restrict__ aatt, int n,
                       float* __restrict__ h, float* __restrict__ ssrc, float* __restrict__ sdst) {
  __shared__ float A[DIN][64];   // 32KB
  int m_base = blockIdx.x * 64;
  int tx = threadIdx.x;
  {
    int m = tx & 63;
    int kq4 = tx >> 6;           // 0..3
    int node = m_base + m;
    bool valid = node < n;
    const float4* x4 = (const float4*)(x + (size_t)node*DIN);
#pragma unroll
    for (int it = 0; it < 8; ++it) {
      int kq = kq4*8 + it;       // 0..31
      int k0 = kq*4;
      float4 v = make_float4(0.f,0.f,0.f,0.f);
      if (valid) v = x4[kq];
      A[k0+0][m] = v.x; A[k0+1][m] = v.y; A[k0+2][m] = v.z; A[k0+3][m] = v.w;
    }
  }
  __syncthreads();

  int c_idx = tx & 31;           // 32 threads cover 64 cols (2 each)
  int m_idx = tx >> 5;           // 8 node groups
  int c0 = c_idx * 2;
  int m0 = m_idx * 8;

  float acc[8][2];
#pragma unroll
  for (int a = 0; a < 8; ++a) { acc[a][0] = 0.f; acc[a][1] = 0.f; }

#pragma unroll 4
  for (int k = 0; k < DIN; ++k) {
    float2 b = *(const float2*)(Win + k*HD + c0);
    float4 a0 = *(const float4*)(&A[k][m0]);
    float4 a1 = *(const float4*)(&A[k][m0+4]);
    float av[8] = {a0.x,a0.y,a0.z,a0.w,a1.x,a1.y,a1.z,a1.w};
#pragma unroll
    for (int a = 0; a < 8; ++a) { acc[a][0] += av[a]*b.x; acc[a][1] += av[a]*b.y; }
  }

  float b0 = bin[c0], b1 = bin[c0+1];
  float a_s0 = aatt[c0],    a_s1 = aatt[c0+1];
  float a_d0 = aatt[HD+c0], a_d1 = aatt[HD+c0+1];

#pragma unroll
  for (int a = 0; a < 8; ++a) {
    int node = m_base + m0 + a;
    float v0 = fmaxf(acc[a][0] + b0, 0.f);
    float v1 = fmaxf(acc[a][1] + b1, 0.f);
    if (node < n) {
      h[(size_t)node*HD + c0]   = v0;
      h[(size_t)node*HD + c0+1] = v1;
    }
    float ps = v0*a_s0 + v1*a_s1;
    float pd = v0*a_d0 + v1*a_d1;
#pragma unroll
    for (int off = 16; off; off >>= 1) { ps += __shfl_xor(ps, off); pd += __shfl_xor(pd, off); }
    if (c_idx == 0 && node < n) { ssrc[node] = ps; sdst[node] = pd; }
  }
}

// ---------------- attention scores: 16-lane group per node ----------------
// writes unnormalized alpha[e] = exp(sc - max) in CSR order, z[node] = sum
__global__ void k_score(const float* __restrict__ ssrc, const float* __restrict__ sdst,
                        const int* __restrict__ rowst, const int* __restrict__ csr, int n,
                        float* __restrict__ alpha, float* __restrict__ z) {
  int g16 = threadIdx.x >> 4;
  int l16 = threadIdx.x & 15;
  int node = blockIdx.x*16 + g16;
  if (node >= n) return;
  int s0 = rowst[node], s1 = rowst[node+1];
  float sdv = sdst[node];
  float mx = -INFINITY;
  for (int i = s0 + l16; i < s1; i += 16) {
    float sc = ssrc[csr[i]] + sdv;
    sc = (sc > 0.f) ? sc : NEG*sc;
    mx = fmaxf(mx, sc);
  }
#pragma unroll
  for (int off = 8; off; off >>= 1) mx = fmaxf(mx, __shfl_xor(mx, off));
  float zs = 0.f;
  for (int i = s0 + l16; i < s1; i += 16) {
    float sc = ssrc[csr[i]] + sdv;
    sc = (sc > 0.f) ? sc : NEG*sc;
    float e = __expf(sc - mx);
    alpha[i] = e;
    zs += e;
  }
#pragma unroll
  for (int off = 8; off; off >>= 1) zs += __shfl_xor(zs, off);
  if (l16 == 0) z[node] = zs;
}

// ---------------- gather pass: wave per node, 4 edges in flight, no serial chain ----------------
__global__ void k_agg2(const float* __restrict__ h, const float* __restrict__ alpha,
                       const float* __restrict__ z, const int* __restrict__ rowst,
                       const int* __restrict__ csr, int n, float* __restrict__ mout) {
  int wid = threadIdx.x >> 6, lane = threadIdx.x & 63;
  int node = blockIdx.x*4 + wid;
  if (node >= n) return;
  int s0 = rowst[node], s1 = rowst[node+1];
  float acc0 = 0.f, acc1 = 0.f, acc2 = 0.f, acc3 = 0.f;
  int i = s0;
  for (; i + 3 < s1; i += 4) {
    int u0 = csr[i], u1 = csr[i+1], u2 = csr[i+2], u3 = csr[i+3];
    float a0 = alpha[i], a1 = alpha[i+1], a2 = alpha[i+2], a3 = alpha[i+3];
    float h0 = h[(size_t)u0*HD + lane];
    float h1 = h[(size_t)u1*HD + lane];
    float h2 = h[(size_t)u2*HD + lane];
    float h3 = h[(size_t)u3*HD + lane];
    acc0 += a0*h0; acc1 += a1*h1; acc2 += a2*h2; acc3 += a3*h3;
  }
  for (; i < s1; ++i)
    acc0 += alpha[i] * h[(size_t)csr[i]*HD + lane];
  float acc = (acc0 + acc1) + (acc2 + acc3);
  mout[(size_t)node*HD + lane] = acc / (z[node] + 1e-16f);
}

// ---------------- GRU as register-blocked fp32 GEMM ----------------
__global__ void __launch_bounds__(256) k_gru2(const float* __restrict__ mm, float* __restrict__ h,
                      const float* __restrict__ B, const float* __restrict__ bc,
                      const float* __restrict__ aatt, int n,
                      float* __restrict__ ssrc, float* __restrict__ sdst) {
  __shared__ float A[128][64];   // 32KB
  int m_base = blockIdx.x * 64;
  int tx = threadIdx.x;
  {
    int m = tx & 63;
    int kq4 = tx >> 6;
    int node = m_base + m;
    bool valid = node < n;
    const float4* m4 = (const float4*)(mm + (size_t)node*HD);
    const float4* h4 = (const float4*)(h  + (size_t)node*HD);
#pragma unroll
    for (int it = 0; it < 8; ++it) {
      int kq = kq4*8 + it;
      int k0 = kq*4;
      float4 v = make_float4(0.f,0.f,0.f,0.f);
      if (valid) v = (kq < 16) ? m4[kq] : h4[kq - 16];
      A[k0+0][m] = v.x; A[k0+1][m] = v.y; A[k0+2][m] = v.z; A[k0+3][m] = v.w;
    }
  }
  __syncthreads();

  int n_idx = tx & 31;
  int m_idx = tx >> 5;
  int c0 = n_idx * 8;            // 8 cols = 2 j's x 4 gates
  int m0 = m_idx * 8;

  float acc[8][8];
#pragma unroll
  for (int a = 0; a < 8; ++a)
#pragma unroll
    for (int b = 0; b < 8; ++b) acc[a][b] = 0.f;

#pragma unroll 4
  for (int k = 0; k < 128; ++k) {
    float4 b0 = *(const float4*)(B + k*256 + c0);
    float4 b1 = *(const float4*)(B + k*256 + c0 + 4);
    float4 a0 = *(const float4*)(&A[k][m0]);
    float4 a1 = *(const float4*)(&A[k][m0+4]);
    float av[8] = {a0.x,a0.y,a0.z,a0.w,a1.x,a1.y,a1.z,a1.w};
    float bv[8] = {b0.x,b0.y,b0.z,b0.w,b1.x,b1.y,b1.z,b1.w};
#pragma unroll
    for (int a = 0; a < 8; ++a)
#pragma unroll
      for (int b = 0; b < 8; ++b) acc[a][b] += av[a]*bv[b];
  }

  float4 bcv0 = *(const float4*)(bc + c0);
  float4 bcv1 = *(const float4*)(bc + c0 + 4);
  float bcr[8] = {bcv0.x,bcv0.y,bcv0.z,bcv0.w,bcv1.x,bcv1.y,bcv1.z,bcv1.w};

  int j0 = c0 >> 2;
  float a_s0 = aatt[j0],    a_s1 = aatt[j0+1];
  float a_d0 = aatt[HD+j0], a_d1 = aatt[HD+j0+1];

#pragma unroll
  for (int a = 0; a < 8; ++a) {
    int ml = m0 + a;
    int node = m_base + ml;
    float ps = 0.f, pd = 0.f;
#pragma unroll
    for (int jj = 0; jj < 2; ++jj) {
      int j = j0 + jj;
      float r   = acc[a][jj*4+0] + bcr[jj*4+0];
      float zz  = acc[a][jj*4+1] + bcr[jj*4+1];
      float gin = acc[a][jj*4+2] + bcr[jj*4+2];
      float ghn = acc[a][jj*4+3] + bcr[jj*4+3];
      float rg = sigmoidf_(r);
      float zg = sigmoidf_(zz);
      float ng = tanhf_(gin + rg*ghn);
      float hold = A[64+j][ml];
      float hnew = (1.f - zg)*ng + zg*hold;
      if (node < n) h[(size_t)node*HD + j] = hnew;
      ps += hnew * (jj ? a_s1 : a_s0);
      pd += hnew * (jj ? a_d1 : a_d0);
    }
#pragma unroll
    for (int off = 16; off; off >>= 1) { ps += __shfl_xor(ps, off); pd += __shfl_xor(pd, off); }
    if (n_idx == 0 && node < n) { ssrc[node] = ps; sdst[node] = pd; }
  }
}

// ---------------- pooling (block per graph) ----------------
__device__ __forceinline__ int lower_bound_i(const int* a, int n, int key) {
  int lo = 0, hi = n;
  while (lo < hi) { int mid = (lo + hi) >> 1; if (a[mid] < key) lo = mid + 1; else hi = mid; }
  return lo;
}

__global__ void k_pool(const float* __restrict__ h, const int* __restrict__ batch, int n,
                       float* __restrict__ gpool) {
  int g = blockIdx.x;
  int lo = lower_bound_i(batch, n, g);
  int hi = lower_bound_i(batch, n, g + 1);
  int wid = threadIdx.x >> 6, lane = threadIdx.x & 63;
  float sum = 0.f, mx = -INFINITY;
  for (int i = lo + wid; i < hi; i += 4) {
    float v = h[(size_t)i*HD + lane];
    sum += v; mx = fmaxf(mx, v);
  }
  __shared__ float ssum[4][HD], smax[4][HD];
  ssum[wid][lane] = sum; smax[wid][lane] = mx;
  __syncthreads();
  if (wid == 0) {
    sum = ssum[0][lane] + ssum[1][lane] + ssum[2][lane] + ssum[3][lane];
    mx = fmaxf(fmaxf(smax[0][lane], smax[1][lane]), fmaxf(smax[2][lane], smax[3][lane]));
    int cnt = hi - lo;
    float mean = sum / fmaxf((float)cnt, 1.f);
    if (cnt <= 0) mx = 0.f;
    gpool[(size_t)g*2*HD + lane] = mean;
    gpool[(size_t)g*2*HD + HD + lane] = mx;
  }
}

// ---------------- MLP head (block per graph, one wave) ----------------
__global__ void k_head(const float* __restrict__ gpool, const float* __restrict__ W1,
                       const float* __restrict__ b1, const float* __restrict__ W2,
                       const float* __restrict__ b2, float* __restrict__ out) {
  int g = blockIdx.x, j = threadIdx.x;
  const float* gr = gpool + (size_t)g*2*HD;
  float acc = b1[j];
#pragma unroll
  for (int k = 0; k < 2*HD; ++k) acc += gr[k] * W1[k*HD + j];
  acc = fmaxf(acc, 0.f);
  float v = acc * W2[j];
#pragma unroll
  for (int off = 32; off; off >>= 1) v += __shfl_xor(v, off);
  if (j == 0) out[g] = v + b2[0];
}

extern "C" void kernel_launch(void* const* d_in, const int* in_sizes, int n_in,
                              void* d_out, int out_size, void* d_ws, size_t ws_size,
                              hipStream_t stream) {
  const float* x     = (const float*)d_in[0];
  const int*   ei    = (const int*)d_in[1];
  const int*   batch = (const int*)d_in[2];
  const float* Win   = (const float*)d_in[3];
  const float* bin   = (const float*)d_in[4];
  const float* aatt  = (const float*)d_in[5];
  const float* Wi    = (const float*)d_in[6];
  const float* Wh    = (const float*)d_in[7];
  const float* bi    = (const float*)d_in[8];
  const float* bh    = (const float*)d_in[9];
  const float* W1    = (const float*)d_in[10];
  const float* b1    = (const float*)d_in[11];
  const float* W2    = (const float*)d_in[12];
  const float* b2    = (const float*)d_in[13];
  float* out = (float*)d_out;

  int N = in_sizes[0] / DIN;
  int E = in_sizes[1] / 2;
  int G = out_size;

  const int* srcp = ei;
  const int* dstp = ei + E;

  char* base = (char*)d_ws;
  size_t off = 0;
  auto alloc = [&](size_t bytes) -> char* {
    char* p = base + off;
    off += (bytes + 255) & ~(size_t)255;
    return p;
  };
  float* h     = (float*)alloc((size_t)N*HD*4);
  float* mbuf  = (float*)alloc((size_t)N*HD*4);
  float* ssrc  = (float*)alloc((size_t)N*4);
  float* sdst  = (float*)alloc((size_t)N*4);
  int*   deg   = (int*)  alloc((size_t)N*4);
  int*   rowst = (int*)  alloc((size_t)(N+1)*4);
  int*   csr   = (int*)  alloc((size_t)E*4);
  float* alpha = (float*)alloc((size_t)E*4);
  float* zbuf  = (float*)alloc((size_t)N*4);
  float* B     = (float*)alloc((size_t)128*256*4);
  float* bc    = (float*)alloc((size_t)256*4);
  float* gpool = (float*)alloc((size_t)G*2*HD*4);
  int*   bsum  = (int*)  alloc(1024);
  (void)ws_size; (void)n_in;

  int nbN = (N + 255)/256, nbE = (E + 255)/256;

  hipMemsetAsync(deg, 0, (size_t)N*4, stream);
  k_count<<<nbE, 256, 0, stream>>>(dstp, E, deg);
  k_scan1<<<nbN, 256, 0, stream>>>(deg, N, rowst, bsum);
  k_scan2<<<1, 256, 0, stream>>>(bsum, nbN);
  k_scan3<<<nbN, 256, 0, stream>>>(rowst, bsum, N, E, deg);
  k_scatter<<<nbE, 256, 0, stream>>>(srcp, dstp, E, rowst, deg, csr);
  k_wt2<<<(128*256 + 255)/256, 256, 0, stream>>>(Wi, Wh, bi, bh, B, bc);
  k_proj2<<<(N + 63)/64, 256, 0, stream>>>(x, Win, bin, aatt, N, h, ssrc, sdst);
  for (int t = 0; t < 3; ++t) {
    k_score<<<(N + 15)/16, 256, 0, stream>>>(ssrc, sdst, rowst, csr, N, alpha, zbuf);
    k_agg2<<<(N + 3)/4, 256, 0, stream>>>(h, alpha, zbuf, rowst, csr, N, mbuf);
    k_gru2<<<(N + 63)/64, 256, 0, stream>>>(mbuf, h, B, bc, aatt, N, ssrc, sdst);
  }
  k_pool<<<G, 256, 0, stream>>>(h, batch, N, gpool);
  k_head<<<G, 64, 0, stream>>>(gpool, W1, b1, W2, b2, out);
}

// Round 4
// 498.773 us; speedup vs baseline: 3.0783x; 1.0499x over previous
//
#include <hip/hip_runtime.h>
#include <math.h>

#define DIN 128
#define HD 64
#define NEG 0.2f

__device__ __forceinline__ float sigmoidf_(float x) { return 1.f / (1.f + __expf(-x)); }
__device__ __forceinline__ float tanhf_(float x)    { return 2.f / (1.f + __expf(-2.f*x)) - 1.f; }

// ---------------- CSR build ----------------
__global__ void k_count(const int* __restrict__ dst, int E, int* __restrict__ deg) {
  int e = blockIdx.x*256 + threadIdx.x;
  if (e < E) atomicAdd(&deg[dst[e]], 1);
}

__global__ void k_scan1(const int* __restrict__ deg, int n, int* __restrict__ rowst, int* __restrict__ bsum) {
  __shared__ int s[256];
  int i = blockIdx.x*256 + threadIdx.x;
  int v = (i < n) ? deg[i] : 0;
  s[threadIdx.x] = v;
  __syncthreads();
  for (int off = 1; off < 256; off <<= 1) {
    int t = (threadIdx.x >= off) ? s[threadIdx.x - off] : 0;
    __syncthreads();
    s[threadIdx.x] += t;
    __syncthreads();
  }
  if (i < n) rowst[i] = s[threadIdx.x] - v;
  if (threadIdx.x == 255) bsum[blockIdx.x] = s[255];
}

__global__ void k_scan2(int* bsum, int nb) {
  __shared__ int s[256];
  int v = (threadIdx.x < nb) ? bsum[threadIdx.x] : 0;
  s[threadIdx.x] = v;
  __syncthreads();
  for (int off = 1; off < 256; off <<= 1) {
    int t = (threadIdx.x >= off) ? s[threadIdx.x - off] : 0;
    __syncthreads();
    s[threadIdx.x] += t;
    __syncthreads();
  }
  if (threadIdx.x < nb) bsum[threadIdx.x] = s[threadIdx.x] - v;
}

__global__ void k_scan3(int* __restrict__ rowst, const int* __restrict__ bsum, int n, int E, int* __restrict__ deg) {
  int i = blockIdx.x*256 + threadIdx.x;
  if (i < n) { rowst[i] += bsum[blockIdx.x]; deg[i] = 0; }
  if (i == 0) rowst[n] = E;
}

__global__ void k_scatter(const int* __restrict__ src, const int* __restrict__ dst, int E,
                          const int* __restrict__ rowst, int* __restrict__ fill, int* __restrict__ csr) {
  int e = blockIdx.x*256 + threadIdx.x;
  if (e < E) {
    int d = dst[e];
    int pos = rowst[d] + atomicAdd(&fill[d], 1);
    csr[pos] = src[e];
  }
}

// ---------------- GRU weight re-layout ----------------
// B[k][c], k in [0,128): k<64 -> m-row (Wi), k>=64 -> h-row (Wh).
// c = j*4 + gate; gate 0: r-sum, 1: z-sum, 2: gi_n (Wi only), 3: gh_n (Wh only)
__global__ void k_wt2(const float* __restrict__ Wi, const float* __restrict__ Wh,
                      const float* __restrict__ bi, const float* __restrict__ bh,
                      float* __restrict__ B, float* __restrict__ bc) {
  int i = blockIdx.x*256 + threadIdx.x;
  if (i < 128*256) {
    int k = i >> 8, c = i & 255;
    int j = c >> 2, g = c & 3;
    float v;
    if (g == 0)      v = (k < 64) ? Wi[k*(3*HD) + j]        : Wh[(k-64)*(3*HD) + j];
    else if (g == 1) v = (k < 64) ? Wi[k*(3*HD) + HD + j]   : Wh[(k-64)*(3*HD) + HD + j];
    else if (g == 2) v = (k < 64) ? Wi[k*(3*HD) + 2*HD + j] : 0.f;
    else             v = (k < 64) ? 0.f                     : Wh[(k-64)*(3*HD) + 2*HD + j];
    B[i] = v;
  }
  if (i < 256) {
    int j = i >> 2, g = i & 3;
    float v;
    if (g == 0)      v = bi[j] + bh[j];
    else if (g == 1) v = bi[HD + j] + bh[HD + j];
    else if (g == 2) v = bi[2*HD + j];
    else             v = bh[2*HD + j];
    bc[i] = v;
  }
}

// ---------------- input projection as register-blocked GEMM (M=32 tile) ----------------
__global__ void __launch_bounds__(256) k_proj2(const float* __restrict__ x, const float* __restrict__ Win,
                       const float* __restrict__ bin, const float* __restrict__ aatt, int n,
                       float* __restrict__ h, float* __restrict__ ssrc, float* __restrict__ sdst) {
  __shared__ float A[DIN][32];   // 16KB
  int m_base = blockIdx.x * 32;
  int tx = threadIdx.x;
  {
    int m = tx & 31;
    int kq8 = tx >> 5;           // 0..7
    int node = m_base + m;
    bool valid = node < n;
    const float4* x4 = (const float4*)(x + (size_t)node*DIN);
#pragma unroll
    for (int it = 0; it < 4; ++it) {
      int kq = kq8*4 + it;       // 0..31
      int k0 = kq*4;
      float4 v = make_float4(0.f,0.f,0.f,0.f);
      if (valid) v = x4[kq];
      A[k0+0][m] = v.x; A[k0+1][m] = v.y; A[k0+2][m] = v.z; A[k0+3][m] = v.w;
    }
  }
  __syncthreads();

  int c_idx = tx & 31;           // 2 cols each
  int m_idx = tx >> 5;           // 8 node groups of 4
  int c0 = c_idx * 2;
  int m0 = m_idx * 4;

  float acc[4][2];
#pragma unroll
  for (int a = 0; a < 4; ++a) { acc[a][0] = 0.f; acc[a][1] = 0.f; }

#pragma unroll 4
  for (int k = 0; k < DIN; ++k) {
    float2 b = *(const float2*)(Win + k*HD + c0);
    float4 a0 = *(const float4*)(&A[k][m0]);
    float av[4] = {a0.x,a0.y,a0.z,a0.w};
#pragma unroll
    for (int a = 0; a < 4; ++a) { acc[a][0] += av[a]*b.x; acc[a][1] += av[a]*b.y; }
  }

  float b0 = bin[c0], b1 = bin[c0+1];
  float a_s0 = aatt[c0],    a_s1 = aatt[c0+1];
  float a_d0 = aatt[HD+c0], a_d1 = aatt[HD+c0+1];

#pragma unroll
  for (int a = 0; a < 4; ++a) {
    int node = m_base + m0 + a;
    float v0 = fmaxf(acc[a][0] + b0, 0.f);
    float v1 = fmaxf(acc[a][1] + b1, 0.f);
    if (node < n) {
      h[(size_t)node*HD + c0]   = v0;
      h[(size_t)node*HD + c0+1] = v1;
    }
    float ps = v0*a_s0 + v1*a_s1;
    float pd = v0*a_d0 + v1*a_d1;
#pragma unroll
    for (int off = 16; off; off >>= 1) { ps += __shfl_xor(ps, off); pd += __shfl_xor(pd, off); }
    if (c_idx == 0 && node < n) { ssrc[node] = ps; sdst[node] = pd; }
  }
}

// ---------------- attention scores: 16-lane group per node ----------------
// pass1: sc -> alpha (contiguous), track max; pass2: alpha = exp(alpha - mx), z = sum
__global__ void k_score(const float* __restrict__ ssrc, const float* __restrict__ sdst,
                        const int* __restrict__ rowst, const int* __restrict__ csr, int n,
                        float* __restrict__ alpha, float* __restrict__ z) {
  int g16 = threadIdx.x >> 4;
  int l16 = threadIdx.x & 15;
  int node = blockIdx.x*16 + g16;
  if (node >= n) return;
  int s0 = rowst[node], s1 = rowst[node+1];
  float sdv = sdst[node];
  float mx = -INFINITY;
  for (int i = s0 + l16; i < s1; i += 16) {
    float sc = ssrc[csr[i]] + sdv;
    sc = (sc > 0.f) ? sc : NEG*sc;
    alpha[i] = sc;
    mx = fmaxf(mx, sc);
  }
#pragma unroll
  for (int off = 8; off; off >>= 1) mx = fmaxf(mx, __shfl_xor(mx, off));
  float zs = 0.f;
  for (int i = s0 + l16; i < s1; i += 16) {
    float e = __expf(alpha[i] - mx);
    alpha[i] = e;
    zs += e;
  }
#pragma unroll
  for (int off = 8; off; off >>= 1) zs += __shfl_xor(zs, off);
  if (l16 == 0) z[node] = zs;
}

// ---------------- gather pass: wave per node, 8 edges in flight ----------------
__global__ void k_agg2(const float* __restrict__ h, const float* __restrict__ alpha,
                       const float* __restrict__ z, const int* __restrict__ rowst,
                       const int* __restrict__ csr, int n, float* __restrict__ mout) {
  int wid = threadIdx.x >> 6, lane = threadIdx.x & 63;
  int node = blockIdx.x*4 + wid;
  if (node >= n) return;
  int s0 = rowst[node], s1 = rowst[node+1];
  float acc0 = 0.f, acc1 = 0.f, acc2 = 0.f, acc3 = 0.f;
  float acc4 = 0.f, acc5 = 0.f, acc6 = 0.f, acc7 = 0.f;
  int i = s0;
  for (; i + 7 < s1; i += 8) {
    int u0 = csr[i],   u1 = csr[i+1], u2 = csr[i+2], u3 = csr[i+3];
    int u4 = csr[i+4], u5 = csr[i+5], u6 = csr[i+6], u7 = csr[i+7];
    float a0 = alpha[i],   a1 = alpha[i+1], a2 = alpha[i+2], a3 = alpha[i+3];
    float a4 = alpha[i+4], a5 = alpha[i+5], a6 = alpha[i+6], a7 = alpha[i+7];
    float h0 = h[(size_t)u0*HD + lane];
    float h1 = h[(size_t)u1*HD + lane];
    float h2 = h[(size_t)u2*HD + lane];
    float h3 = h[(size_t)u3*HD + lane];
    float h4 = h[(size_t)u4*HD + lane];
    float h5 = h[(size_t)u5*HD + lane];
    float h6 = h[(size_t)u6*HD + lane];
    float h7 = h[(size_t)u7*HD + lane];
    acc0 += a0*h0; acc1 += a1*h1; acc2 += a2*h2; acc3 += a3*h3;
    acc4 += a4*h4; acc5 += a5*h5; acc6 += a6*h6; acc7 += a7*h7;
  }
  for (; i < s1; ++i)
    acc0 += alpha[i] * h[(size_t)csr[i]*HD + lane];
  float acc = ((acc0 + acc1) + (acc2 + acc3)) + ((acc4 + acc5) + (acc6 + acc7));
  mout[(size_t)node*HD + lane] = acc / (z[node] + 1e-16f);
}

// ---------------- GRU as register-blocked fp32 GEMM (M=32 tile) ----------------
__global__ void __launch_bounds__(256) k_gru2(const float* __restrict__ mm, float* __restrict__ h,
                      const float* __restrict__ B, const float* __restrict__ bc,
                      const float* __restrict__ aatt, int n,
                      float* __restrict__ ssrc, float* __restrict__ sdst) {
  __shared__ float A[128][32];   // 16KB
  int m_base = blockIdx.x * 32;
  int tx = threadIdx.x;
  {
    int m = tx & 31;
    int kq8 = tx >> 5;           // 0..7
    int node = m_base + m;
    bool valid = node < n;
    const float4* m4 = (const float4*)(mm + (size_t)node*HD);
    const float4* h4 = (const float4*)(h  + (size_t)node*HD);
#pragma unroll
    for (int it = 0; it < 4; ++it) {
      int kq = kq8*4 + it;       // 0..31
      int k0 = kq*4;
      float4 v = make_float4(0.f,0.f,0.f,0.f);
      if (valid) v = (kq < 16) ? m4[kq] : h4[kq - 16];
      A[k0+0][m] = v.x; A[k0+1][m] = v.y; A[k0+2][m] = v.z; A[k0+3][m] = v.w;
    }
  }
  __syncthreads();

  int n_idx = tx & 31;
  int m_idx = tx >> 5;           // 0..7
  int c0 = n_idx * 8;            // 8 cols = 2 j's x 4 gates
  int m0 = m_idx * 4;            // 4 nodes

  float acc[4][8];
#pragma unroll
  for (int a = 0; a < 4; ++a)
#pragma unroll
    for (int b = 0; b < 8; ++b) acc[a][b] = 0.f;

#pragma unroll 4
  for (int k = 0; k < 128; ++k) {
    float4 b0 = *(const float4*)(B + k*256 + c0);
    float4 b1 = *(const float4*)(B + k*256 + c0 + 4);
    float4 a0 = *(const float4*)(&A[k][m0]);
    float av[4] = {a0.x,a0.y,a0.z,a0.w};
    float bv[8] = {b0.x,b0.y,b0.z,b0.w,b1.x,b1.y,b1.z,b1.w};
#pragma unroll
    for (int a = 0; a < 4; ++a)
#pragma unroll
      for (int b = 0; b < 8; ++b) acc[a][b] += av[a]*bv[b];
  }

  float4 bcv0 = *(const float4*)(bc + c0);
  float4 bcv1 = *(const float4*)(bc + c0 + 4);
  float bcr[8] = {bcv0.x,bcv0.y,bcv0.z,bcv0.w,bcv1.x,bcv1.y,bcv1.z,bcv1.w};

  int j0 = c0 >> 2;
  float a_s0 = aatt[j0],    a_s1 = aatt[j0+1];
  float a_d0 = aatt[HD+j0], a_d1 = aatt[HD+j0+1];

#pragma unroll
  for (int a = 0; a < 4; ++a) {
    int ml = m0 + a;
    int node = m_base + ml;
    float ps = 0.f, pd = 0.f;
#pragma unroll
    for (int jj = 0; jj < 2; ++jj) {
      int j = j0 + jj;
      float r   = acc[a][jj*4+0] + bcr[jj*4+0];
      float zz  = acc[a][jj*4+1] + bcr[jj*4+1];
      float gin = acc[a][jj*4+2] + bcr[jj*4+2];
      float ghn = acc[a][jj*4+3] + bcr[jj*4+3];
      float rg = sigmoidf_(r);
      float zg = sigmoidf_(zz);
      float ng = tanhf_(gin + rg*ghn);
      float hold = A[64+j][ml];
      float hnew = (1.f - zg)*ng + zg*hold;
      if (node < n) h[(size_t)node*HD + j] = hnew;
      ps += hnew * (jj ? a_s1 : a_s0);
      pd += hnew * (jj ? a_d1 : a_d0);
    }
#pragma unroll
    for (int off = 16; off; off >>= 1) { ps += __shfl_xor(ps, off); pd += __shfl_xor(pd, off); }
    if (n_idx == 0 && node < n) { ssrc[node] = ps; sdst[node] = pd; }
  }
}

// ---------------- pooling: two-stage ----------------
__device__ __forceinline__ int lower_bound_i(const int* a, int n, int key) {
  int lo = 0, hi = n;
  while (lo < hi) { int mid = (lo + hi) >> 1; if (a[mid] < key) lo = mid + 1; else hi = mid; }
  return lo;
}

// stage 1: 8 slices per graph, 1 wave per (graph, slice)
__global__ void k_pool1(const float* __restrict__ h, const int* __restrict__ batch, int n,
                        float* __restrict__ psum, float* __restrict__ pmax) {
  int g = blockIdx.x >> 3, slice = blockIdx.x & 7;
  int lane = threadIdx.x;            // 64 lanes = HD
  int lo = lower_bound_i(batch, n, g);
  int hi = lower_bound_i(batch, n, g + 1);
  int span = hi - lo;
  int s0 = lo + (int)(((long long)span * slice) >> 3);
  int s1 = lo + (int)(((long long)span * (slice + 1)) >> 3);
  float sum0 = 0.f, sum1 = 0.f, sum2 = 0.f, sum3 = 0.f;
  float mx0 = -INFINITY, mx1 = -INFINITY, mx2 = -INFINITY, mx3 = -INFINITY;
  int i = s0;
  for (; i + 3 < s1; i += 4) {
    float v0 = h[(size_t)(i+0)*HD + lane];
    float v1 = h[(size_t)(i+1)*HD + lane];
    float v2 = h[(size_t)(i+2)*HD + lane];
    float v3 = h[(size_t)(i+3)*HD + lane];
    sum0 += v0; sum1 += v1; sum2 += v2; sum3 += v3;
    mx0 = fmaxf(mx0, v0); mx1 = fmaxf(mx1, v1); mx2 = fmaxf(mx2, v2); mx3 = fmaxf(mx3, v3);
  }
  for (; i < s1; ++i) {
    float v = h[(size_t)i*HD + lane];
    sum0 += v; mx0 = fmaxf(mx0, v);
  }
  float sum = (sum0 + sum1) + (sum2 + sum3);
  float mx = fmaxf(fmaxf(mx0, mx1), fmaxf(mx2, mx3));
  psum[(size_t)blockIdx.x*HD + lane] = sum;
  pmax[(size_t)blockIdx.x*HD + lane] = mx;
}

// stage 2: reduce 8 partials, write mean||max
__global__ void k_pool2(const float* __restrict__ psum, const float* __restrict__ pmax,
                        const int* __restrict__ batch, int n, float* __restrict__ gpool) {
  int g = blockIdx.x;
  int lane = threadIdx.x;
  int lo = lower_bound_i(batch, n, g);
  int hi = lower_bound_i(batch, n, g + 1);
  int cnt = hi - lo;
  float sum = 0.f, mx = -INFINITY;
#pragma unroll
  for (int s = 0; s < 8; ++s) {
    sum += psum[(size_t)(g*8+s)*HD + lane];
    mx = fmaxf(mx, pmax[(size_t)(g*8+s)*HD + lane]);
  }
  float mean = sum / fmaxf((float)cnt, 1.f);
  if (cnt <= 0 || !isfinite(mx)) mx = 0.f;
  gpool[(size_t)g*2*HD + lane] = mean;
  gpool[(size_t)g*2*HD + HD + lane] = mx;
}

// ---------------- MLP head (block per graph, one wave) ----------------
__global__ void k_head(const float* __restrict__ gpool, const float* __restrict__ W1,
                       const float* __restrict__ b1, const float* __restrict__ W2,
                       const float* __restrict__ b2, float* __restrict__ out) {
  int g = blockIdx.x, j = threadIdx.x;
  const float* gr = gpool + (size_t)g*2*HD;
  float acc = b1[j];
#pragma unroll
  for (int k = 0; k < 2*HD; ++k) acc += gr[k] * W1[k*HD + j];
  acc = fmaxf(acc, 0.f);
  float v = acc * W2[j];
#pragma unroll
  for (int off = 32; off; off >>= 1) v += __shfl_xor(v, off);
  if (j == 0) out[g] = v + b2[0];
}

extern "C" void kernel_launch(void* const* d_in, const int* in_sizes, int n_in,
                              void* d_out, int out_size, void* d_ws, size_t ws_size,
                              hipStream_t stream) {
  const float* x     = (const float*)d_in[0];
  const int*   ei    = (const int*)d_in[1];
  const int*   batch = (const int*)d_in[2];
  const float* Win   = (const float*)d_in[3];
  const float* bin   = (const float*)d_in[4];
  const float* aatt  = (const float*)d_in[5];
  const float* Wi    = (const float*)d_in[6];
  const float* Wh    = (const float*)d_in[7];
  const float* bi    = (const float*)d_in[8];
  const float* bh    = (const float*)d_in[9];
  const float* W1    = (const float*)d_in[10];
  const float* b1    = (const float*)d_in[11];
  const float* W2    = (const float*)d_in[12];
  const float* b2    = (const float*)d_in[13];
  float* out = (float*)d_out;

  int N = in_sizes[0] / DIN;
  int E = in_sizes[1] / 2;
  int G = out_size;

  const int* srcp = ei;
  const int* dstp = ei + E;

  char* base = (char*)d_ws;
  size_t off = 0;
  auto alloc = [&](size_t bytes) -> char* {
    char* p = base + off;
    off += (bytes + 255) & ~(size_t)255;
    return p;
  };
  float* h     = (float*)alloc((size_t)N*HD*4);
  float* mbuf  = (float*)alloc((size_t)N*HD*4);
  float* ssrc  = (float*)alloc((size_t)N*4);
  float* sdst  = (float*)alloc((size_t)N*4);
  int*   deg   = (int*)  alloc((size_t)N*4);
  int*   rowst = (int*)  alloc((size_t)(N+1)*4);
  int*   csr   = (int*)  alloc((size_t)E*4);
  float* alpha = (float*)alloc((size_t)E*4);
  float* zbuf  = (float*)alloc((size_t)N*4);
  float* B     = (float*)alloc((size_t)128*256*4);
  float* bc    = (float*)alloc((size_t)256*4);
  float* gpool = (float*)alloc((size_t)G*2*HD*4);
  float* psum  = (float*)alloc((size_t)G*8*HD*4);
  float* pmax  = (float*)alloc((size_t)G*8*HD*4);
  int*   bsum  = (int*)  alloc(1024);
  (void)ws_size; (void)n_in;

  int nbN = (N + 255)/256, nbE = (E + 255)/256;

  hipMemsetAsync(deg, 0, (size_t)N*4, stream);
  k_count<<<nbE, 256, 0, stream>>>(dstp, E, deg);
  k_scan1<<<nbN, 256, 0, stream>>>(deg, N, rowst, bsum);
  k_scan2<<<1, 256, 0, stream>>>(bsum, nbN);
  k_scan3<<<nbN, 256, 0, stream>>>(rowst, bsum, N, E, deg);
  k_scatter<<<nbE, 256, 0, stream>>>(srcp, dstp, E, rowst, deg, csr);
  k_wt2<<<(128*256 + 255)/256, 256, 0, stream>>>(Wi, Wh, bi, bh, B, bc);
  k_proj2<<<(N + 31)/32, 256, 0, stream>>>(x, Win, bin, aatt, N, h, ssrc, sdst);
  for (int t = 0; t < 3; ++t) {
    k_score<<<(N + 15)/16, 256, 0, stream>>>(ssrc, sdst, rowst, csr, N, alpha, zbuf);
    k_agg2<<<(N + 3)/4, 256, 0, stream>>>(h, alpha, zbuf, rowst, csr, N, mbuf);
    k_gru2<<<(N + 31)/32, 256, 0, stream>>>(mbuf, h, B, bc, aatt, N, ssrc, sdst);
  }
  k_pool1<<<G*8, 64, 0, stream>>>(h, batch, N, psum, pmax);
  k_pool2<<<G, 64, 0, stream>>>(psum, pmax, batch, N, gpool);
  k_head<<<G, 64, 0, stream>>>(gpool, W1, b1, W2, b2, out);
}

// Round 5
// 461.538 us; speedup vs baseline: 3.3267x; 1.0807x over previous
//
#include <hip/hip_runtime.h>
#include <math.h>

#define DIN 128
#define HD 64
#define NEG 0.2f

__device__ __forceinline__ float sigmoidf_(float x) { return 1.f / (1.f + __expf(-x)); }
__device__ __forceinline__ float tanhf_(float x)    { return 2.f / (1.f + __expf(-2.f*x)) - 1.f; }

// ---------------- CSR build ----------------
__global__ void k_count(const int* __restrict__ dst, int E, int* __restrict__ deg) {
  int e = blockIdx.x*256 + threadIdx.x;
  if (e < E) atomicAdd(&deg[dst[e]], 1);
}

__global__ void k_scan1(const int* __restrict__ deg, int n, int* __restrict__ rowst, int* __restrict__ bsum) {
  __shared__ int s[256];
  int i = blockIdx.x*256 + threadIdx.x;
  int v = (i < n) ? deg[i] : 0;
  s[threadIdx.x] = v;
  __syncthreads();
  for (int off = 1; off < 256; off <<= 1) {
    int t = (threadIdx.x >= off) ? s[threadIdx.x - off] : 0;
    __syncthreads();
    s[threadIdx.x] += t;
    __syncthreads();
  }
  if (i < n) rowst[i] = s[threadIdx.x] - v;
  if (threadIdx.x == 255) bsum[blockIdx.x] = s[255];
}

__global__ void k_scan2(int* bsum, int nb) {
  __shared__ int s[256];
  int v = (threadIdx.x < nb) ? bsum[threadIdx.x] : 0;
  s[threadIdx.x] = v;
  __syncthreads();
  for (int off = 1; off < 256; off <<= 1) {
    int t = (threadIdx.x >= off) ? s[threadIdx.x - off] : 0;
    __syncthreads();
    s[threadIdx.x] += t;
    __syncthreads();
  }
  if (threadIdx.x < nb) bsum[threadIdx.x] = s[threadIdx.x] - v;
}

__global__ void k_scan3(int* __restrict__ rowst, const int* __restrict__ bsum, int n, int E, int* __restrict__ deg) {
  int i = blockIdx.x*256 + threadIdx.x;
  if (i < n) { rowst[i] += bsum[blockIdx.x]; deg[i] = 0; }
  if (i == 0) rowst[n] = E;
}

__global__ void k_scatter(const int* __restrict__ src, const int* __restrict__ dst, int E,
                          const int* __restrict__ rowst, int* __restrict__ fill, int* __restrict__ csr) {
  int e = blockIdx.x*256 + threadIdx.x;
  if (e < E) {
    int d = dst[e];
    int pos = rowst[d] + atomicAdd(&fill[d], 1);
    csr[pos] = src[e];
  }
}

// ---------------- GRU weight re-layout ----------------
// B[k][c], k in [0,128): k<64 -> m-row (Wi), k>=64 -> h-row (Wh).
// c = j*4 + gate; gate 0: r-sum, 1: z-sum, 2: gi_n (Wi only), 3: gh_n (Wh only)
__global__ void k_wt2(const float* __restrict__ Wi, const float* __restrict__ Wh,
                      const float* __restrict__ bi, const float* __restrict__ bh,
                      float* __restrict__ B, float* __restrict__ bc) {
  int i = blockIdx.x*256 + threadIdx.x;
  if (i < 128*256) {
    int k = i >> 8, c = i & 255;
    int j = c >> 2, g = c & 3;
    float v;
    if (g == 0)      v = (k < 64) ? Wi[k*(3*HD) + j]        : Wh[(k-64)*(3*HD) + j];
    else if (g == 1) v = (k < 64) ? Wi[k*(3*HD) + HD + j]   : Wh[(k-64)*(3*HD) + HD + j];
    else if (g == 2) v = (k < 64) ? Wi[k*(3*HD) + 2*HD + j] : 0.f;
    else             v = (k < 64) ? 0.f                     : Wh[(k-64)*(3*HD) + 2*HD + j];
    B[i] = v;
  }
  if (i < 256) {
    int j = i >> 2, g = i & 3;
    float v;
    if (g == 0)      v = bi[j] + bh[j];
    else if (g == 1) v = bi[HD + j] + bh[HD + j];
    else if (g == 2) v = bi[2*HD + j];
    else             v = bh[2*HD + j];
    bc[i] = v;
  }
}

// ---------------- input projection as register-blocked GEMM (M=32 tile) ----------------
__global__ void __launch_bounds__(256) k_proj2(const float* __restrict__ x, const float* __restrict__ Win,
                       const float* __restrict__ bin, const float* __restrict__ aatt, int n,
                       float* __restrict__ h, float* __restrict__ ssrc, float* __restrict__ sdst) {
  __shared__ float A[DIN][32];   // 16KB
  int m_base = blockIdx.x * 32;
  int tx = threadIdx.x;
  {
    int m = tx & 31;
    int kq8 = tx >> 5;           // 0..7
    int node = m_base + m;
    bool valid = node < n;
    const float4* x4 = (const float4*)(x + (size_t)node*DIN);
#pragma unroll
    for (int it = 0; it < 4; ++it) {
      int kq = kq8*4 + it;       // 0..31
      int k0 = kq*4;
      float4 v = make_float4(0.f,0.f,0.f,0.f);
      if (valid) v = x4[kq];
      A[k0+0][m] = v.x; A[k0+1][m] = v.y; A[k0+2][m] = v.z; A[k0+3][m] = v.w;
    }
  }
  __syncthreads();

  int c_idx = tx & 31;           // 2 cols each
  int m_idx = tx >> 5;           // 8 node groups of 4
  int c0 = c_idx * 2;
  int m0 = m_idx * 4;

  float acc[4][2];
#pragma unroll
  for (int a = 0; a < 4; ++a) { acc[a][0] = 0.f; acc[a][1] = 0.f; }

#pragma unroll 4
  for (int k = 0; k < DIN; ++k) {
    float2 b = *(const float2*)(Win + k*HD + c0);
    float4 a0 = *(const float4*)(&A[k][m0]);
    float av[4] = {a0.x,a0.y,a0.z,a0.w};
#pragma unroll
    for (int a = 0; a < 4; ++a) { acc[a][0] += av[a]*b.x; acc[a][1] += av[a]*b.y; }
  }

  float b0 = bin[c0], b1 = bin[c0+1];
  float a_s0 = aatt[c0],    a_s1 = aatt[c0+1];
  float a_d0 = aatt[HD+c0], a_d1 = aatt[HD+c0+1];

#pragma unroll
  for (int a = 0; a < 4; ++a) {
    int node = m_base + m0 + a;
    float v0 = fmaxf(acc[a][0] + b0, 0.f);
    float v1 = fmaxf(acc[a][1] + b1, 0.f);
    if (node < n) {
      h[(size_t)node*HD + c0]   = v0;
      h[(size_t)node*HD + c0+1] = v1;
    }
    float ps = v0*a_s0 + v1*a_s1;
    float pd = v0*a_d0 + v1*a_d1;
#pragma unroll
    for (int off = 16; off; off >>= 1) { ps += __shfl_xor(ps, off); pd += __shfl_xor(pd, off); }
    if (c_idx == 0 && node < n) { ssrc[node] = ps; sdst[node] = pd; }
  }
}

// ---------------- attention scores: 16-lane group per node ----------------
__global__ void k_score(const float* __restrict__ ssrc, const float* __restrict__ sdst,
                        const int* __restrict__ rowst, const int* __restrict__ csr, int n,
                        float* __restrict__ alpha, float* __restrict__ z) {
  int g16 = threadIdx.x >> 4;
  int l16 = threadIdx.x & 15;
  int node = blockIdx.x*16 + g16;
  if (node >= n) return;
  int s0 = rowst[node], s1 = rowst[node+1];
  float sdv = sdst[node];
  float mx = -INFINITY;
  for (int i = s0 + l16; i < s1; i += 16) {
    float sc = ssrc[csr[i]] + sdv;
    sc = (sc > 0.f) ? sc : NEG*sc;
    alpha[i] = sc;
    mx = fmaxf(mx, sc);
  }
#pragma unroll
  for (int off = 8; off; off >>= 1) mx = fmaxf(mx, __shfl_xor(mx, off));
  float zs = 0.f;
  for (int i = s0 + l16; i < s1; i += 16) {
    float e = __expf(alpha[i] - mx);
    alpha[i] = e;
    zs += e;
  }
#pragma unroll
  for (int off = 8; off; off >>= 1) zs += __shfl_xor(zs, off);
  if (l16 == 0) z[node] = zs;
}

// ---------------- gather pass: 2 nodes per wave (32-lane halves, float2/lane), 4 edges in flight ----------------
__global__ void k_agg3(const float* __restrict__ h, const float* __restrict__ alpha,
                       const float* __restrict__ z, const int* __restrict__ rowst,
                       const int* __restrict__ csr, int n, float* __restrict__ mout) {
  int wid = threadIdx.x >> 6;
  int lane = threadIdx.x & 63;
  int half = lane >> 5, l32 = lane & 31;
  int node = blockIdx.x*8 + wid*2 + half;
  if (node >= n) return;
  int s0 = rowst[node], s1 = rowst[node+1];
  float2 acc0 = make_float2(0.f,0.f), acc1 = make_float2(0.f,0.f);
  float2 acc2 = make_float2(0.f,0.f), acc3 = make_float2(0.f,0.f);
  int i = s0;
  for (; i + 3 < s1; i += 4) {
    int u0 = csr[i], u1 = csr[i+1], u2 = csr[i+2], u3 = csr[i+3];
    float a0 = alpha[i], a1 = alpha[i+1], a2 = alpha[i+2], a3 = alpha[i+3];
    float2 h0 = *((const float2*)(h + (size_t)u0*HD) + l32);
    float2 h1 = *((const float2*)(h + (size_t)u1*HD) + l32);
    float2 h2 = *((const float2*)(h + (size_t)u2*HD) + l32);
    float2 h3 = *((const float2*)(h + (size_t)u3*HD) + l32);
    acc0.x += a0*h0.x; acc0.y += a0*h0.y;
    acc1.x += a1*h1.x; acc1.y += a1*h1.y;
    acc2.x += a2*h2.x; acc2.y += a2*h2.y;
    acc3.x += a3*h3.x; acc3.y += a3*h3.y;
  }
  for (; i < s1; ++i) {
    float a0 = alpha[i];
    float2 h0 = *((const float2*)(h + (size_t)csr[i]*HD) + l32);
    acc0.x += a0*h0.x; acc0.y += a0*h0.y;
  }
  float zi = 1.f / (z[node] + 1e-16f);
  float2 r;
  r.x = ((acc0.x + acc1.x) + (acc2.x + acc3.x)) * zi;
  r.y = ((acc0.y + acc1.y) + (acc2.y + acc3.y)) * zi;
  *((float2*)(mout + (size_t)node*HD) + l32) = r;
}

// ---------------- GRU as software-pipelined register-blocked fp32 GEMM (M=64 tile) ----------------
__global__ void __launch_bounds__(256, 3) k_gru3(const float* __restrict__ mm, float* __restrict__ h,
                      const float* __restrict__ B, const float* __restrict__ bc,
                      const float* __restrict__ aatt, int n,
                      float* __restrict__ ssrc, float* __restrict__ sdst) {
  __shared__ float A[128][64];   // 32KB: rows 0..63 = m, rows 64..127 = h
  int m_base = blockIdx.x * 64;
  int tx = threadIdx.x;
  {
    int m = tx & 63;
    int kq4 = tx >> 6;           // 0..3
    int node = m_base + m;
    bool valid = node < n;
    const float4* m4 = (const float4*)(mm + (size_t)node*HD);
    const float4* h4 = (const float4*)(h  + (size_t)node*HD);
#pragma unroll
    for (int it = 0; it < 8; ++it) {
      int kq = kq4*8 + it;       // 0..31
      int k0 = kq*4;
      float4 v = make_float4(0.f,0.f,0.f,0.f);
      if (valid) v = (kq < 16) ? m4[kq] : h4[kq - 16];
      A[k0+0][m] = v.x; A[k0+1][m] = v.y; A[k0+2][m] = v.z; A[k0+3][m] = v.w;
    }
  }
  __syncthreads();

  int n_idx = tx & 31;
  int m_idx = tx >> 5;           // 0..7
  int c0 = n_idx * 8;            // 8 cols = 2 j's x 4 gates
  int m0 = m_idx * 8;            // 8 nodes
  int j0 = c0 >> 2;              // = n_idx*2

  float acc[8][8];
#pragma unroll
  for (int a = 0; a < 8; ++a)
#pragma unroll
    for (int b = 0; b < 8; ++b) acc[a][b] = 0.f;

  const float4* Brow = (const float4*)B + (c0 >> 2);   // row stride 64 float4

  // prologue: k = 0
  float4 b0c = Brow[0];
  float4 b1c = Brow[1];
  float4 a0c = *(const float4*)(&A[0][m0]);
  float4 a1c = *(const float4*)(&A[0][m0+4]);

#pragma unroll 4
  for (int k = 0; k < 127; ++k) {
    // prefetch k+1 while computing k
    float4 b0n = Brow[(size_t)(k+1)*64];
    float4 b1n = Brow[(size_t)(k+1)*64 + 1];
    float4 a0n = *(const float4*)(&A[k+1][m0]);
    float4 a1n = *(const float4*)(&A[k+1][m0+4]);
    float av[8] = {a0c.x,a0c.y,a0c.z,a0c.w,a1c.x,a1c.y,a1c.z,a1c.w};
    float bv[8] = {b0c.x,b0c.y,b0c.z,b0c.w,b1c.x,b1c.y,b1c.z,b1c.w};
#pragma unroll
    for (int a = 0; a < 8; ++a)
#pragma unroll
      for (int b = 0; b < 8; ++b) acc[a][b] += av[a]*bv[b];
    b0c = b0n; b1c = b1n; a0c = a0n; a1c = a1n;
  }
  { // k = 127
    float av[8] = {a0c.x,a0c.y,a0c.z,a0c.w,a1c.x,a1c.y,a1c.z,a1c.w};
    float bv[8] = {b0c.x,b0c.y,b0c.z,b0c.w,b1c.x,b1c.y,b1c.z,b1c.w};
#pragma unroll
    for (int a = 0; a < 8; ++a)
#pragma unroll
      for (int b = 0; b < 8; ++b) acc[a][b] += av[a]*bv[b];
  }

  float4 bcv0 = *(const float4*)(bc + c0);
  float4 bcv1 = *(const float4*)(bc + c0 + 4);
  float bcr[8] = {bcv0.x,bcv0.y,bcv0.z,bcv0.w,bcv1.x,bcv1.y,bcv1.z,bcv1.w};

  // h_old: coalesced float2 per node (avoids 32-way LDS bank conflict)
  float2 ho[8];
#pragma unroll
  for (int a = 0; a < 8; ++a) {
    int node = m_base + m0 + a;
    ho[a] = (node < n) ? *(const float2*)(h + (size_t)node*HD + j0)
                       : make_float2(0.f, 0.f);
  }

  float a_s0 = aatt[j0],    a_s1 = aatt[j0+1];
  float a_d0 = aatt[HD+j0], a_d1 = aatt[HD+j0+1];

#pragma unroll
  for (int a = 0; a < 8; ++a) {
    int node = m_base + m0 + a;
    float hn[2];
#pragma unroll
    for (int jj = 0; jj < 2; ++jj) {
      float r   = acc[a][jj*4+0] + bcr[jj*4+0];
      float zz  = acc[a][jj*4+1] + bcr[jj*4+1];
      float gin = acc[a][jj*4+2] + bcr[jj*4+2];
      float ghn = acc[a][jj*4+3] + bcr[jj*4+3];
      float rg = sigmoidf_(r);
      float zg = sigmoidf_(zz);
      float ng = tanhf_(gin + rg*ghn);
      float hold = jj ? ho[a].y : ho[a].x;
      hn[jj] = (1.f - zg)*ng + zg*hold;
    }
    if (node < n)
      *(float2*)(h + (size_t)node*HD + j0) = make_float2(hn[0], hn[1]);
    float ps = hn[0]*a_s0 + hn[1]*a_s1;
    float pd = hn[0]*a_d0 + hn[1]*a_d1;
#pragma unroll
    for (int off = 16; off; off >>= 1) { ps += __shfl_xor(ps, off); pd += __shfl_xor(pd, off); }
    if (n_idx == 0 && node < n) { ssrc[node] = ps; sdst[node] = pd; }
  }
}

// ---------------- pooling: two-stage ----------------
__device__ __forceinline__ int lower_bound_i(const int* a, int n, int key) {
  int lo = 0, hi = n;
  while (lo < hi) { int mid = (lo + hi) >> 1; if (a[mid] < key) lo = mid + 1; else hi = mid; }
  return lo;
}

__global__ void k_pool1(const float* __restrict__ h, const int* __restrict__ batch, int n,
                        float* __restrict__ psum, float* __restrict__ pmax) {
  int g = blockIdx.x >> 3, slice = blockIdx.x & 7;
  int lane = threadIdx.x;            // 64 lanes = HD
  int lo = lower_bound_i(batch, n, g);
  int hi = lower_bound_i(batch, n, g + 1);
  int span = hi - lo;
  int s0 = lo + (int)(((long long)span * slice) >> 3);
  int s1 = lo + (int)(((long long)span * (slice + 1)) >> 3);
  float sum0 = 0.f, sum1 = 0.f, sum2 = 0.f, sum3 = 0.f;
  float mx0 = -INFINITY, mx1 = -INFINITY, mx2 = -INFINITY, mx3 = -INFINITY;
  int i = s0;
  for (; i + 3 < s1; i += 4) {
    float v0 = h[(size_t)(i+0)*HD + lane];
    float v1 = h[(size_t)(i+1)*HD + lane];
    float v2 = h[(size_t)(i+2)*HD + lane];
    float v3 = h[(size_t)(i+3)*HD + lane];
    sum0 += v0; sum1 += v1; sum2 += v2; sum3 += v3;
    mx0 = fmaxf(mx0, v0); mx1 = fmaxf(mx1, v1); mx2 = fmaxf(mx2, v2); mx3 = fmaxf(mx3, v3);
  }
  for (; i < s1; ++i) {
    float v = h[(size_t)i*HD + lane];
    sum0 += v; mx0 = fmaxf(mx0, v);
  }
  float sum = (sum0 + sum1) + (sum2 + sum3);
  float mx = fmaxf(fmaxf(mx0, mx1), fmaxf(mx2, mx3));
  psum[(size_t)blockIdx.x*HD + lane] = sum;
  pmax[(size_t)blockIdx.x*HD + lane] = mx;
}

__global__ void k_pool2(const float* __restrict__ psum, const float* __restrict__ pmax,
                        const int* __restrict__ batch, int n, float* __restrict__ gpool) {
  int g = blockIdx.x;
  int lane = threadIdx.x;
  int lo = lower_bound_i(batch, n, g);
  int hi = lower_bound_i(batch, n, g + 1);
  int cnt = hi - lo;
  float sum = 0.f, mx = -INFINITY;
#pragma unroll
  for (int s = 0; s < 8; ++s) {
    sum += psum[(size_t)(g*8+s)*HD + lane];
    mx = fmaxf(mx, pmax[(size_t)(g*8+s)*HD + lane]);
  }
  float mean = sum / fmaxf((float)cnt, 1.f);
  if (cnt <= 0 || !isfinite(mx)) mx = 0.f;
  gpool[(size_t)g*2*HD + lane] = mean;
  gpool[(size_t)g*2*HD + HD + lane] = mx;
}

// ---------------- MLP head (block per graph, one wave) ----------------
__global__ void k_head(const float* __restrict__ gpool, const float* __restrict__ W1,
                       const float* __restrict__ b1, const float* __restrict__ W2,
                       const float* __restrict__ b2, float* __restrict__ out) {
  int g = blockIdx.x, j = threadIdx.x;
  const float* gr = gpool + (size_t)g*2*HD;
  float acc = b1[j];
#pragma unroll
  for (int k = 0; k < 2*HD; ++k) acc += gr[k] * W1[k*HD + j];
  acc = fmaxf(acc, 0.f);
  float v = acc * W2[j];
#pragma unroll
  for (int off = 32; off; off >>= 1) v += __shfl_xor(v, off);
  if (j == 0) out[g] = v + b2[0];
}

extern "C" void kernel_launch(void* const* d_in, const int* in_sizes, int n_in,
                              void* d_out, int out_size, void* d_ws, size_t ws_size,
                              hipStream_t stream) {
  const float* x     = (const float*)d_in[0];
  const int*   ei    = (const int*)d_in[1];
  const int*   batch = (const int*)d_in[2];
  const float* Win   = (const float*)d_in[3];
  const float* bin   = (const float*)d_in[4];
  const float* aatt  = (const float*)d_in[5];
  const float* Wi    = (const float*)d_in[6];
  const float* Wh    = (const float*)d_in[7];
  const float* bi    = (const float*)d_in[8];
  const float* bh    = (const float*)d_in[9];
  const float* W1    = (const float*)d_in[10];
  const float* b1    = (const float*)d_in[11];
  const float* W2    = (const float*)d_in[12];
  const float* b2    = (const float*)d_in[13];
  float* out = (float*)d_out;

  int N = in_sizes[0] / DIN;
  int E = in_sizes[1] / 2;
  int G = out_size;

  const int* srcp = ei;
  const int* dstp = ei + E;

  char* base = (char*)d_ws;
  size_t off = 0;
  auto alloc = [&](size_t bytes) -> char* {
    char* p = base + off;
    off += (bytes + 255) & ~(size_t)255;
    return p;
  };
  float* h     = (float*)alloc((size_t)N*HD*4);
  float* mbuf  = (float*)alloc((size_t)N*HD*4);
  float* ssrc  = (float*)alloc((size_t)N*4);
  float* sdst  = (float*)alloc((size_t)N*4);
  int*   deg   = (int*)  alloc((size_t)N*4);
  int*   rowst = (int*)  alloc((size_t)(N+1)*4);
  int*   csr   = (int*)  alloc((size_t)E*4);
  float* alpha = (float*)alloc((size_t)E*4);
  float* zbuf  = (float*)alloc((size_t)N*4);
  float* B     = (float*)alloc((size_t)128*256*4);
  float* bc    = (float*)alloc((size_t)256*4);
  float* gpool = (float*)alloc((size_t)G*2*HD*4);
  float* psum  = (float*)alloc((size_t)G*8*HD*4);
  float* pmax  = (float*)alloc((size_t)G*8*HD*4);
  int*   bsum  = (int*)  alloc(1024);
  (void)ws_size; (void)n_in;

  int nbN = (N + 255)/256, nbE = (E + 255)/256;

  hipMemsetAsync(deg, 0, (size_t)N*4, stream);
  k_count<<<nbE, 256, 0, stream>>>(dstp, E, deg);
  k_scan1<<<nbN, 256, 0, stream>>>(deg, N, rowst, bsum);
  k_scan2<<<1, 256, 0, stream>>>(bsum, nbN);
  k_scan3<<<nbN, 256, 0, stream>>>(rowst, bsum, N, E, deg);
  k_scatter<<<nbE, 256, 0, stream>>>(srcp, dstp, E, rowst, deg, csr);
  k_wt2<<<(128*256 + 255)/256, 256, 0, stream>>>(Wi, Wh, bi, bh, B, bc);
  k_proj2<<<(N + 31)/32, 256, 0, stream>>>(x, Win, bin, aatt, N, h, ssrc, sdst);
  for (int t = 0; t < 3; ++t) {
    k_score<<<(N + 15)/16, 256, 0, stream>>>(ssrc, sdst, rowst, csr, N, alpha, zbuf);
    k_agg3<<<(N + 7)/8, 256, 0, stream>>>(h, alpha, zbuf, rowst, csr, N, mbuf);
    k_gru3<<<(N + 63)/64, 256, 0, stream>>>(mbuf, h, B, bc, aatt, N, ssrc, sdst);
  }
  k_pool1<<<G*8, 64, 0, stream>>>(h, batch, N, psum, pmax);
  k_pool2<<<G, 64, 0, stream>>>(psum, pmax, batch, N, gpool);
  k_head<<<G, 64, 0, stream>>>(gpool, W1, b1, W2, b2, out);
}